// Round 6
// baseline (711.157 us; speedup 1.0000x reference)
//
#include <hip/hip_runtime.h>
#include <hip/hip_bf16.h>
#include <math.h>

// Problem constants
#define NH    16
#define NOPE  128
#define ROPED 64
#define VD    128
#define QLR   1536
#define IH    8
#define ID    128
#define TOPK  8
#define EPSF  1e-5f
#define B_    2
#define S_    2048
#define H_    2048

using bf16 = __hip_bfloat16;
typedef __attribute__((ext_vector_type(8))) short short8;
typedef __attribute__((ext_vector_type(4))) short short4v;
typedef __attribute__((ext_vector_type(4))) float f32x4;

#define GLOBAL_AS __attribute__((address_space(1)))
#define LDS_AS    __attribute__((address_space(3)))

__device__ __forceinline__ float b2f(bf16 v) { return __bfloat162float(v); }
__device__ __forceinline__ bf16 f2b(float v) { return __float2bfloat16(v); }
__device__ __forceinline__ void stoC(float* p, float v) { *p = v; }
__device__ __forceinline__ void stoC(bf16* p, float v) { *p = __float2bfloat16(v); }

// ---------------------------------------------------------------------------
// Dedicated gate projection (exact fp32, verified R4).
// ---------------------------------------------------------------------------
__global__ __launch_bounds__(256) void gate_k(const float* __restrict__ x,
                                              const float* __restrict__ Wg,
                                              float* __restrict__ gate) {
    const int t = threadIdx.x;
    const int wid = t >> 6, lane = t & 63;
    const int row = blockIdx.x * 4 + wid;
    const float* xp = x + (size_t)row * H_;

    float acc[8] = {};
    for (int k0 = 0; k0 < H_; k0 += 256) {
        const int kb = k0 + lane * 4;
        const f32x4 xv = *(const f32x4*)(xp + kb);
        const f32x4 w0 = *(const f32x4*)(Wg + (size_t)kb * 8);
        const f32x4 w1 = *(const f32x4*)(Wg + (size_t)kb * 8 + 4);
        const f32x4 w2 = *(const f32x4*)(Wg + (size_t)(kb + 1) * 8);
        const f32x4 w3 = *(const f32x4*)(Wg + (size_t)(kb + 1) * 8 + 4);
        const f32x4 w4 = *(const f32x4*)(Wg + (size_t)(kb + 2) * 8);
        const f32x4 w5 = *(const f32x4*)(Wg + (size_t)(kb + 2) * 8 + 4);
        const f32x4 w6 = *(const f32x4*)(Wg + (size_t)(kb + 3) * 8);
        const f32x4 w7 = *(const f32x4*)(Wg + (size_t)(kb + 3) * 8 + 4);
#pragma unroll
        for (int j = 0; j < 4; j++) {
            acc[j]     += xv[0] * w0[j] + xv[1] * w2[j] + xv[2] * w4[j] + xv[3] * w6[j];
            acc[4 + j] += xv[0] * w1[j] + xv[1] * w3[j] + xv[2] * w5[j] + xv[3] * w7[j];
        }
    }
#pragma unroll
    for (int j = 0; j < 8; j++) {
#pragma unroll
        for (int off = 32; off > 0; off >>= 1)
            acc[j] += __shfl_xor(acc[j], off);
    }
    if (lane == 0) {
#pragma unroll
        for (int j = 0; j < 8; j++) gate[(size_t)row * 8 + j] = acc[j];
    }
}

// ---------------------------------------------------------------------------
// bf16 MFMA GEMM, m97 structure + bijective chunked XCD swizzle.
// ---------------------------------------------------------------------------
template <typename OT>
__global__ __launch_bounds__(256) void gemm_bt_mfma_k(const bf16* __restrict__ A,
                                                      const bf16* __restrict__ Bt,
                                                      OT* __restrict__ C,
                                                      int M, int N, int K) {
    __shared__ bf16 As[128 * 32];
    __shared__ bf16 Bs[128 * 32];
    const int t = threadIdx.x;
    const int w = t >> 6;
    const int l = t & 63;
    const int col = l & 15;
    const int quad = l >> 4;
    const int wm = w >> 1, wn = w & 1;

    const int gx = gridDim.x;
    const int nwg = gx * gridDim.y;
    const int lin = blockIdx.y * gx + blockIdx.x;
    const int work = (lin & 7) * (nwg >> 3) + (lin >> 3);
    const int row0 = (work / gx) * 128;
    const int col0 = (work % gx) * 128;

    const int rA = l >> 2;
    const int cA = (l & 3) * 8;
    const bf16* ga0 = A + (size_t)(row0 + w * 16 + rA) * K + cA;
    const bf16* ga1 = A + (size_t)(row0 + (4 + w) * 16 + rA) * K + cA;
    const bf16* gb0 = Bt + (size_t)(col0 + w * 16 + rA) * K + cA;
    const bf16* gb1 = Bt + (size_t)(col0 + (4 + w) * 16 + rA) * K + cA;
    bf16* lA0 = &As[w * 512];
    bf16* lA1 = &As[(4 + w) * 512];
    bf16* lB0 = &Bs[w * 512];
    bf16* lB1 = &Bs[(4 + w) * 512];

    f32x4 acc[4][4];
#pragma unroll
    for (int i = 0; i < 4; i++)
#pragma unroll
        for (int j = 0; j < 4; j++) acc[i][j] = (f32x4){0.f, 0.f, 0.f, 0.f};

    for (int k0 = 0; k0 < K; k0 += 32) {
        __syncthreads();
        __builtin_amdgcn_global_load_lds((const GLOBAL_AS void*)(ga0 + k0),
                                         (LDS_AS void*)lA0, 16, 0, 0);
        __builtin_amdgcn_global_load_lds((const GLOBAL_AS void*)(ga1 + k0),
                                         (LDS_AS void*)lA1, 16, 0, 0);
        __builtin_amdgcn_global_load_lds((const GLOBAL_AS void*)(gb0 + k0),
                                         (LDS_AS void*)lB0, 16, 0, 0);
        __builtin_amdgcn_global_load_lds((const GLOBAL_AS void*)(gb1 + k0),
                                         (LDS_AS void*)lB1, 16, 0, 0);
        __syncthreads();

        short8 af[4], bfr[4];
#pragma unroll
        for (int i = 0; i < 4; i++) {
            af[i]  = *(const short8*)&As[(wm * 64 + i * 16 + col) * 32 + quad * 8];
            bfr[i] = *(const short8*)&Bs[(wn * 64 + i * 16 + col) * 32 + quad * 8];
        }
#pragma unroll
        for (int i = 0; i < 4; i++)
#pragma unroll
            for (int j = 0; j < 4; j++)
                acc[i][j] = __builtin_amdgcn_mfma_f32_16x16x32_bf16(af[i], bfr[j], acc[i][j], 0, 0, 0);
    }

#pragma unroll
    for (int i = 0; i < 4; i++)
#pragma unroll
        for (int j = 0; j < 4; j++)
#pragma unroll
            for (int r = 0; r < 4; r++) {
                const int gr = row0 + wm * 64 + i * 16 + quad * 4 + r;
                const int gc = col0 + wn * 64 + j * 16 + col;
                stoC(C + (size_t)gr * N + gc, acc[i][j][r]);
            }
}

// ---------------------------------------------------------------------------
// kv matmul on MFMA (verified R5). col-block 0 -> kvc k_nope; col-block 1 ->
// VbT[bh][dv][s] packed 8B stores.
// ---------------------------------------------------------------------------
__global__ __launch_bounds__(256) void gemm_kv_k(const bf16* __restrict__ A,
                                                 const bf16* __restrict__ Bt,
                                                 bf16* __restrict__ kvc,
                                                 bf16* __restrict__ VbT) {
    __shared__ bf16 As[128 * 32];
    __shared__ bf16 Bs[128 * 32];
    const int K = 128;
    const int t = threadIdx.x;
    const int w = t >> 6;
    const int l = t & 63;
    const int col = l & 15;
    const int quad = l >> 4;
    const int wm = w >> 1, wn = w & 1;

    const int gx = gridDim.x;
    const int nwg = gx * gridDim.y;
    const int lin = blockIdx.y * gx + blockIdx.x;
    const int work = (lin & 7) * (nwg >> 3) + (lin >> 3);
    const int row0 = (work / gx) * 128;
    const int col0 = (work % gx) * 128;

    const int rA = l >> 2;
    const int cA = (l & 3) * 8;
    const bf16* ga0 = A + (size_t)(row0 + w * 16 + rA) * K + cA;
    const bf16* ga1 = A + (size_t)(row0 + (4 + w) * 16 + rA) * K + cA;
    const bf16* gb0 = Bt + (size_t)(col0 + w * 16 + rA) * K + cA;
    const bf16* gb1 = Bt + (size_t)(col0 + (4 + w) * 16 + rA) * K + cA;
    bf16* lA0 = &As[w * 512];
    bf16* lA1 = &As[(4 + w) * 512];
    bf16* lB0 = &Bs[w * 512];
    bf16* lB1 = &Bs[(4 + w) * 512];

    f32x4 acc[4][4];
#pragma unroll
    for (int i = 0; i < 4; i++)
#pragma unroll
        for (int j = 0; j < 4; j++) acc[i][j] = (f32x4){0.f, 0.f, 0.f, 0.f};

    for (int k0 = 0; k0 < K; k0 += 32) {
        __syncthreads();
        __builtin_amdgcn_global_load_lds((const GLOBAL_AS void*)(ga0 + k0),
                                         (LDS_AS void*)lA0, 16, 0, 0);
        __builtin_amdgcn_global_load_lds((const GLOBAL_AS void*)(ga1 + k0),
                                         (LDS_AS void*)lA1, 16, 0, 0);
        __builtin_amdgcn_global_load_lds((const GLOBAL_AS void*)(gb0 + k0),
                                         (LDS_AS void*)lB0, 16, 0, 0);
        __builtin_amdgcn_global_load_lds((const GLOBAL_AS void*)(gb1 + k0),
                                         (LDS_AS void*)lB1, 16, 0, 0);
        __syncthreads();

        short8 af[4], bfr[4];
#pragma unroll
        for (int i = 0; i < 4; i++) {
            af[i]  = *(const short8*)&As[(wm * 64 + i * 16 + col) * 32 + quad * 8];
            bfr[i] = *(const short8*)&Bs[(wn * 64 + i * 16 + col) * 32 + quad * 8];
        }
#pragma unroll
        for (int i = 0; i < 4; i++)
#pragma unroll
            for (int j = 0; j < 4; j++)
                acc[i][j] = __builtin_amdgcn_mfma_f32_16x16x32_bf16(af[i], bfr[j], acc[i][j], 0, 0, 0);
    }

    if (col0 == 0) {
#pragma unroll
        for (int i = 0; i < 4; i++)
#pragma unroll
            for (int j = 0; j < 4; j++)
#pragma unroll
                for (int r = 0; r < 4; r++) {
                    const int gr = row0 + wm * 64 + i * 16 + quad * 4 + r;
                    const int gc = wn * 64 + j * 16 + col;
                    kvc[(size_t)gr * 192 + gc] = f2b(acc[i][j][r]);
                }
    } else {
        const int bb = row0 >> 15;
        const int ssb = ((row0 >> 4) & (S_ - 1)) + wm * 4;
#pragma unroll
        for (int j = 0; j < 4; j++) {
            const int dv = wn * 64 + j * 16 + col;
#pragma unroll
            for (int r = 0; r < 4; r++) {
                const int hh = quad * 4 + r;
                short4v pk;
#pragma unroll
                for (int i = 0; i < 4; i++) {
                    bf16 v = f2b(acc[i][j][r]);
                    pk[i] = *(short*)&v;
                }
                *(short4v*)&VbT[((size_t)(bb * NH + hh) * 128 + dv) * S_ + ssb] = pk;
            }
        }
    }
}

// ---------------------------------------------------------------------------
// Wave-per-row LN of kv_nope -> bf16 kvn, plus RoPE of k_pe.
// ---------------------------------------------------------------------------
__global__ __launch_bounds__(256) void kv_ln_k(bf16* __restrict__ kvc,
                                               const float* __restrict__ knw,
                                               const float* __restrict__ knb,
                                               bf16* __restrict__ kvn) {
    const int idx = blockIdx.x * 4 + (threadIdx.x >> 6);   // row 0..65535
    const int lane = threadIdx.x & 63;
    const int s = (idx >> 4) & (S_ - 1);
    const size_t base = (size_t)idx * 192;

    const float v0 = b2f(kvc[base + 64 + lane]);
    const float v1 = b2f(kvc[base + 128 + lane]);
    float xr = 0.f, xi = 0.f;
    if (lane < 32) { xr = b2f(kvc[base + 2 * lane]); xi = b2f(kvc[base + 2 * lane + 1]); }

    float s1 = v0 + v1, s2 = v0 * v0 + v1 * v1;
#pragma unroll
    for (int off = 32; off > 0; off >>= 1) {
        s1 += __shfl_xor(s1, off);
        s2 += __shfl_xor(s2, off);
    }
    const float mu = s1 * (1.f / 128.f);
    const float rinv = rsqrtf(s2 * (1.f / 128.f) - mu * mu + EPSF);
    kvn[(size_t)idx * 128 + lane]      = f2b((v0 - mu) * rinv * knw[lane] + knb[lane]);
    kvn[(size_t)idx * 128 + lane + 64] = f2b((v1 - mu) * rinv * knw[lane + 64] + knb[lane + 64]);

    if (lane < 32) {
        const float freq = exp2f(-0.41524101186092014f * (float)lane); // 10000^(-2l/64)
        const float ang = (float)s * freq;
        float sn, c; sincosf(ang, &sn, &c);
        kvc[base + 128 + 2 * lane]     = f2b(xr * c - xi * sn);
        kvc[base + 128 + 2 * lane + 1] = f2b(xr * sn + xi * c);
    }
}

// ---------------------------------------------------------------------------
// Elementwise fp32 -> bf16 cast.
// ---------------------------------------------------------------------------
__global__ __launch_bounds__(256) void cast_bf16_k(const float* __restrict__ X,
                                                   bf16* __restrict__ Y, int n4) {
    for (int i = blockIdx.x * 256 + threadIdx.x; i < n4; i += gridDim.x * 256) {
        const f32x4 v = ((const f32x4*)X)[i];
        short4v o;
#pragma unroll
        for (int j = 0; j < 4; j++) {
            bf16 b = f2b(v[j]);
            o[j] = *(short*)&b;
        }
        ((short4v*)Y)[i] = o;
    }
}

// ---------------------------------------------------------------------------
// Tiled transpose-cast: W (KxN fp32) -> Wt (NxK bf16).
// ---------------------------------------------------------------------------
__global__ __launch_bounds__(256) void transpose_cast_k(const float* __restrict__ W,
                                                        bf16* __restrict__ Wt,
                                                        int K, int N) {
    __shared__ float tile[32][33];
    const int t = threadIdx.x;
    const int tx = t & 31, ty = t >> 5;
    const int n0 = blockIdx.x * 32;
    const int k0 = blockIdx.y * 32;
#pragma unroll
    for (int i = 0; i < 4; i++)
        tile[ty + 8 * i][tx] = W[(size_t)(k0 + ty + 8 * i) * N + n0 + tx];
    __syncthreads();
#pragma unroll
    for (int i = 0; i < 4; i++)
        Wt[(size_t)(n0 + ty + 8 * i) * K + k0 + tx] = f2b(tile[tx][ty + 8 * i]);
}

// ---------------------------------------------------------------------------
// Row layernorm emitting bf16.
// ---------------------------------------------------------------------------
__global__ __launch_bounds__(256) void layernorm_cast_k(const float* __restrict__ X,
                                                        const float* __restrict__ w,
                                                        const float* __restrict__ b,
                                                        bf16* __restrict__ Y,
                                                        int L) {
    __shared__ float r1[256], r2[256];
    const int row = blockIdx.x;
    const int t = threadIdx.x;
    const float* xp = X + (size_t)row * L;
    bf16* yp = Y + (size_t)row * L;
    float s1 = 0.f, s2 = 0.f;
    for (int j = t; j < L; j += 256) { const float v = xp[j]; s1 += v; s2 += v * v; }
    r1[t] = s1; r2[t] = s2; __syncthreads();
    for (int off = 128; off > 0; off >>= 1) {
        if (t < off) { r1[t] += r1[t + off]; r2[t] += r2[t + off]; }
        __syncthreads();
    }
    const float mu   = r1[0] / (float)L;
    const float var  = r2[0] / (float)L - mu * mu;
    const float rinv = rsqrtf(var + EPSF);
    for (int j = t; j < L; j += 256)
        yp[j] = f2b((xp[j] - mu) * rinv * w[j] + b[j]);
}

// ---------------------------------------------------------------------------
// In-place RoPE on qp.
// ---------------------------------------------------------------------------
__global__ __launch_bounds__(256) void q_rope_k(bf16* __restrict__ qp) {
    const int total = B_ * S_ * NH * 32;
    for (int p = blockIdx.x * 256 + threadIdx.x; p < total; p += gridDim.x * 256) {
        const int j = p & 31;
        const int row = p >> 5;
        const int sr = row >> 4;
        const int s = sr & (S_ - 1);
        const size_t base = (size_t)row * 192 + 128 + 2 * j;
        const float xr = b2f(qp[base]);
        const float xi = b2f(qp[base + 1]);
        const float freq = exp2f(-0.41524101186092014f * (float)j); // 10000^(-2j/64)
        const float ang = (float)s * freq;
        float sn, c; sincosf(ang, &sn, &c);
        qp[base]     = f2b(xr * c - xi * sn);
        qp[base + 1] = f2b(xr * sn + xi * c);
    }
}

// ---------------------------------------------------------------------------
// Sparse branch (unchanged).
// ---------------------------------------------------------------------------
__global__ __launch_bounds__(256) void sparse_k(const float* __restrict__ gate,
                                                const float* __restrict__ ist,
                                                const float* __restrict__ Wsq,
                                                const float* __restrict__ Wsk,
                                                const float* __restrict__ Wsv,
                                                const float* __restrict__ Wio,
                                                float* __restrict__ io) {
    __shared__ float g[S_];
    __shared__ float sel[TOPK][ID];
    __shared__ float sq[TOPK][ID], sk[TOPK][ID], sv[TOPK][ID];
    __shared__ float sp[TOPK][TOPK];
    __shared__ float ms[ID];
    __shared__ float rv[256];
    __shared__ int ri[256];
    __shared__ int sidx[TOPK];
    const int bi = blockIdx.x;
    const int ih = bi % IH;
    const int b = bi / IH;
    const int t = threadIdx.x;

    for (int s = t; s < S_; s += 256) g[s] = gate[(size_t)(b * S_ + s) * IH + ih];
    __syncthreads();

    for (int r = 0; r < TOPK; r++) {
        float bv = -INFINITY; int bx = S_;
        for (int s = t; s < S_; s += 256) {
            const float v = g[s];
            if (v > bv) { bv = v; bx = s; }
        }
        rv[t] = bv; ri[t] = bx; __syncthreads();
        for (int off = 128; off > 0; off >>= 1) {
            if (t < off) {
                const float v2 = rv[t + off]; const int i2 = ri[t + off];
                if (v2 > rv[t] || (v2 == rv[t] && i2 < ri[t])) { rv[t] = v2; ri[t] = i2; }
            }
            __syncthreads();
        }
        if (t == 0) { sidx[r] = ri[0]; g[ri[0]] = -INFINITY; }
        __syncthreads();
    }

    for (int i = t; i < TOPK * ID; i += 256) {
        const int r = i >> 7, d = i & 127;
        sel[r][d] = ist[((size_t)(b * S_ + sidx[r]) * IH + ih) * ID + d];
    }
    __syncthreads();

    for (int i = t; i < TOPK * ID; i += 256) {
        const int r = i >> 7, n = i & 127;
        float aq = 0.f, ak = 0.f, av = 0.f;
        for (int k = 0; k < 128; k++) {
            const float s = sel[r][k];
            aq += s * Wsq[k * ID + n];
            ak += s * Wsk[k * ID + n];
            av += s * Wsv[k * ID + n];
        }
        sq[r][n] = aq; sk[r][n] = ak; sv[r][n] = av;
    }
    __syncthreads();

    if (t < TOPK * TOPK) {
        const int r = t >> 3, c = t & 7;
        float a = 0.f;
        for (int k = 0; k < 128; k++) a += sq[r][k] * sk[c][k];
        sp[r][c] = a * 0.08838834764831845f;
    }
    __syncthreads();

    if (t < TOPK) {
        float m = -INFINITY;
        for (int c = 0; c < 8; c++) m = fmaxf(m, sp[t][c]);
        float e[8]; float sum = 0.f;
        for (int c = 0; c < 8; c++) { e[c] = expf(sp[t][c] - m); sum += e[c]; }
        for (int c = 0; c < 8; c++) sp[t][c] = e[c] / sum;
    }
    __syncthreads();

    if (t < ID) {
        float acc = 0.f;
        for (int r = 0; r < 8; r++) {
            float so = 0.f;
            for (int c = 0; c < 8; c++) so += sp[r][c] * sv[c][t];
            acc += so;
        }
        ms[t] = acc * 0.125f;
    }
    __syncthreads();

    if (t < ID) {
        float acc = 0.f;
        for (int k = 0; k < 128; k++) acc += ms[k] * Wio[(size_t)k * H_ + t];
        io[((size_t)b * IH + ih) * ID + t] = acc;
    }
}

// ---------------------------------------------------------------------------
// MFMA flash attention v4:
//  - R5 structure (q-tile pairs, KVBLK=64, VbT staging, setprio, XCD swz)
//  - io_s LDS removed -> 53,248 B total (3 blocks/CU target; launch_bounds
//    (256,3) caps VGPR at 170 to hold 3 waves/SIMD)
//  - Software-pipelined staging (T14): regs for tile kt+1 loaded during
//    compute of tile kt; ds_writes happen between the two barriers only.
//  - Defer-max (T13, THR=8): skip alpha rescale while tile max growth <= 8.
// ---------------------------------------------------------------------------
__global__ __launch_bounds__(256, 3) void attn_mfma_k(const bf16* __restrict__ Qp,
                                                      const bf16* __restrict__ Kc,
                                                      const bf16* __restrict__ VbT,
                                                      const float* __restrict__ io,
                                                      bf16* __restrict__ O) {
    __shared__ unsigned short Kt[64 * 200];    // 64 keys x 192 dims (+8 pad)
    __shared__ unsigned short Vt[128 * 72];    // V^T: 128 dv x 64 keys (+8 pad)
    __shared__ unsigned short Ps[4 * 16 * 72]; // per-wave P patch 16q x 64k (+8)

    // Chunked XCD swizzle (bijective: 512 = 8 * 64)
    const int lin = blockIdx.x + 16 * blockIdx.y + 256 * blockIdx.z;
    const int swz = (lin & 7) * 64 + (lin >> 3);
    const int pairi = swz & 15;
    const int h = (swz >> 4) & 15;
    const int b = swz >> 8;

    const int t = threadIdx.x;
    const int lane = t & 63;
    const int wq = t >> 6;
    const int col = lane & 15;
    const int quad = lane >> 4;

    const float scale = 0.07216878364870322f;  // 1/sqrt(192)
    const bf16* vplane = VbT + (size_t)(b * NH + h) * 128 * (size_t)S_;

    // Staging source/dest geometry (fixed per thread)
    const int kr = t >> 2;                 // K row 0..63
    const int kc0 = (t & 3) * 48;          // K col chunk
    const int vki0 = (t & 7) * 8;          // V ki chunk
    const int vdv = t >> 3;                // V dv base (0..31), +32p

#pragma unroll 1
    for (int ti = 0; ti < 2; ti++) {
        const int qt = (ti == 0) ? pairi : 31 - pairi;
        const int q0 = qt * 64;

        short8 qfrag[6];
        {
            const int q = q0 + wq * 16 + col;
            const short8* qrow = (const short8*)(Qp + ((size_t)(b * S_ + q) * NH + h) * 192);
#pragma unroll
            for (int kc = 0; kc < 6; kc++) qfrag[kc] = qrow[kc * 4 + quad];
        }

        float m_r[4], l_r[4];
#pragma unroll
        for (int r = 0; r < 4; r++) { m_r[r] = -1e30f; l_r[r] = 0.f; }
        f32x4 accO[8];
#pragma unroll
        for (int nt = 0; nt < 8; nt++) accO[nt] = (f32x4){0.f, 0.f, 0.f, 0.f};

        const int nkt = qt + 1;

        // Prologue: load tile 0 into registers
        short8 kreg[6], vreg[4];
        {
            const short8* ksrc = (const short8*)(Kc + ((size_t)(b * S_ + kr) * NH + h) * 192 + kc0);
#pragma unroll
            for (int c = 0; c < 6; c++) kreg[c] = ksrc[c];
#pragma unroll
            for (int p = 0; p < 4; p++)
                vreg[p] = *(const short8*)(vplane + (size_t)(p * 32 + vdv) * S_ + vki0);
        }

        for (int kt = 0; kt < nkt; kt++) {
            const int kt0 = kt * 64;
            __syncthreads();   // previous tile's LDS readers done
            // Commit staged registers to LDS
            {
                short8* dst = (short8*)&Kt[kr * 200 + kc0];
#pragma unroll
                for (int c = 0; c < 6; c++) dst[c] = kreg[c];
#pragma unroll
                for (int p = 0; p < 4; p++)
                    *(short8*)&Vt[(p * 32 + vdv) * 72 + vki0] = vreg[p];
            }
            __syncthreads();   // tile ready

            // Issue next tile's global loads (latency hides under compute)
            if (kt + 1 < nkt) {
                const int nk0 = kt0 + 64;
                const short8* ksrc = (const short8*)(Kc + ((size_t)(b * S_ + nk0 + kr) * NH + h) * 192 + kc0);
#pragma unroll
                for (int c = 0; c < 6; c++) kreg[c] = ksrc[c];
#pragma unroll
                for (int p = 0; p < 4; p++)
                    vreg[p] = *(const short8*)(vplane + (size_t)(p * 32 + vdv) * S_ + nk0 + vki0);
            }

            // Scores: four 16-key n-tiles, K=192 in 6 mfma steps each.
            f32x4 s[4];
            __builtin_amdgcn_s_setprio(1);
#pragma unroll
            for (int nt = 0; nt < 4; nt++) {
                f32x4 acc = (f32x4){0.f, 0.f, 0.f, 0.f};
#pragma unroll
                for (int kc = 0; kc < 6; kc++) {
                    const short8 kf = *(const short8*)&Kt[(nt * 16 + col) * 200 + kc * 32 + quad * 8];
                    acc = __builtin_amdgcn_mfma_f32_16x16x32_bf16(qfrag[kc], kf, acc, 0, 0, 0);
                }
                s[nt] = acc;
            }
            __builtin_amdgcn_s_setprio(0);
            // Scale + causal mask
#pragma unroll
            for (int nt = 0; nt < 4; nt++)
#pragma unroll
                for (int r = 0; r < 4; r++) {
                    const int kg = kt0 + nt * 16 + col;
                    const int qg = q0 + wq * 16 + quad * 4 + r;
                    const float v = s[nt][r] * scale;
                    s[nt][r] = (kg > qg) ? -1e30f : v;
                }
            // Online softmax with defer-max (THR=8)
            float alpha[4];
#pragma unroll
            for (int r = 0; r < 4; r++) {
                float mt = fmaxf(fmaxf(s[0][r], s[1][r]), fmaxf(s[2][r], s[3][r]));
                mt = fmaxf(mt, __shfl_xor(mt, 1));
                mt = fmaxf(mt, __shfl_xor(mt, 2));
                mt = fmaxf(mt, __shfl_xor(mt, 4));
                mt = fmaxf(mt, __shfl_xor(mt, 8));
                const bool need = (mt > m_r[r] + 8.f);
                const float mn = need ? mt : m_r[r];
                alpha[r] = need ? __expf(m_r[r] - mn) : 1.f;
                m_r[r] = mn;
                float rs = 0.f;
#pragma unroll
                for (int nt = 0; nt < 4; nt++) {
                    const float p = __expf(s[nt][r] - mn);
                    s[nt][r] = p;
                    rs += p;
                }
                rs += __shfl_xor(rs, 1);
                rs += __shfl_xor(rs, 2);
                rs += __shfl_xor(rs, 4);
                rs += __shfl_xor(rs, 8);
                l_r[r] = l_r[r] * alpha[r] + rs;
            }
            // P (C-layout) -> bf16 LDS -> reread in A-layout (per-wave region).
            {
                unsigned short* pw = &Ps[wq * 1152];
#pragma unroll
                for (int nt = 0; nt < 4; nt++)
#pragma unroll
                    for (int r = 0; r < 4; r++) {
                        bf16 hv = f2b(s[nt][r]);
                        pw[(quad * 4 + r) * 72 + nt * 16 + col] = *(unsigned short*)&hv;
                    }
            }
            short8 pf[2];
#pragma unroll
            for (int kk = 0; kk < 2; kk++)
                pf[kk] = *(const short8*)&Ps[wq * 1152 + col * 72 + kk * 32 + quad * 8];
            // Rescale O only when some row actually moved its max
            if (!(alpha[0] == 1.f && alpha[1] == 1.f && alpha[2] == 1.f && alpha[3] == 1.f)) {
#pragma unroll
                for (int nt = 0; nt < 8; nt++)
#pragma unroll
                    for (int r = 0; r < 4; r++) accO[nt][r] *= alpha[r];
            }
            __builtin_amdgcn_s_setprio(1);
#pragma unroll
            for (int nt = 0; nt < 8; nt++) {
#pragma unroll
                for (int kk = 0; kk < 2; kk++) {
                    const short8 vf = *(const short8*)&Vt[(nt * 16 + col) * 72 + kk * 32 + quad * 8];
                    accO[nt] = __builtin_amdgcn_mfma_f32_16x16x32_bf16(pf[kk], vf, accO[nt], 0, 0, 0);
                }
            }
            __builtin_amdgcn_s_setprio(0);
        }

        // Epilogue (io read direct from global; 8 KB, L2-hot)
        const float* iorow = io + ((size_t)b * IH + (h >> 1)) * ID;
        float rinv[4];
#pragma unroll
        for (int r = 0; r < 4; r++) rinv[r] = 1.f / l_r[r];
#pragma unroll
        for (int nt = 0; nt < 8; nt++) {
            const int dv = nt * 16 + col;
            const float iov = iorow[dv];
#pragma unroll
            for (int r = 0; r < 4; r++) {
                const int q = q0 + wq * 16 + quad * 4 + r;
                O[((size_t)(b * S_ + q) * NH + h) * VD + dv] = f2b(accO[nt][r] * rinv[r] + iov);
            }
        }
    }
}

// ---------------------------------------------------------------------------
// Workspace lifetime plan (within proven ~100.8 MB):
//   rbig @0 (33.5MB): cq fp32 -> { ist fp32 [0,16M) ; kvn bf16 [16M,32M) }
//                      -> attnb bf16 [0,16M)
//   qp   @32MB (25.2MB)
//   kvc  @56MB (25.2MB): cq_bf16 (pre-kvc) -> kvc
//   VbT/Wt @80MB (16.8MB): Wt transposes -> VbT -> Wt(W_o)
//   gate @96MB (131KB): gate -> WkvT (64KB, post-sparse)
//   iob  @96MB+128KB
//   x_bf16 lives in d_out (dead before the final GEMM writes out).
// ---------------------------------------------------------------------------
extern "C" void kernel_launch(void* const* d_in, const int* in_sizes, int n_in,
                              void* d_out, int out_size, void* d_ws, size_t ws_size,
                              hipStream_t stream) {
    const float* x      = (const float*)d_in[0];
    const float* W_cq   = (const float*)d_in[1];
    const float* qn_w   = (const float*)d_in[2];
    const float* qn_b   = (const float*)d_in[3];
    const float* W_q    = (const float*)d_in[4];
    const float* W_ckv  = (const float*)d_in[5];
    const float* kvn_w  = (const float*)d_in[6];
    const float* kvn_b  = (const float*)d_in[7];
    const float* W_kv   = (const float*)d_in[8];
    const float* W_o    = (const float*)d_in[9];
    const float* W_ip   = (const float*)d_in[10];
    const float* W_ig   = (const float*)d_in[11];
    const float* W_sq   = (const float*)d_in[12];
    const float* W_sk   = (const float*)d_in[13];
    const float* W_sv   = (const float*)d_in[14];
    const float* W_io   = (const float*)d_in[15];
    float* out = (float*)d_out;

    const int M = B_ * S_;

    char* wsb = (char*)d_ws;
    float* rbig  = (float*)wsb;
    bf16*  kvn   = (bf16*)(wsb + 16777216);   // upper half of rbig
    bf16*  qp    = (bf16*)(wsb + 33554432);
    bf16*  kvc   = (bf16*)(wsb + 58720256);
    bf16*  cqb   = (bf16*)(wsb + 58720256);   // alias kvc (dead before kvc)
    bf16*  VbT   = (bf16*)(wsb + 83886080);
    bf16*  Wt    = (bf16*)(wsb + 83886080);   // alias VbT (disjoint lifetimes)
    float* gate  = (float*)(wsb + 100663296);
    bf16*  WkvT  = (bf16*)(wsb + 100663296);  // alias gate (post-sparse)
    float* iob   = (float*)(wsb + 100794368);
    float* cq    = rbig;
    float* ist   = rbig;
    bf16*  attnb = (bf16*)rbig;
    bf16*  xb    = (bf16*)d_out;              // x_bf16 in output buffer

    dim3 blk(256);

    // Stage 0: casts
    cast_bf16_k<<<dim3(2048), blk, 0, stream>>>(x, xb, M * H_ / 4);

    // qc = LN(x @ W_cq)
    transpose_cast_k<<<dim3(QLR / 32, H_ / 32), blk, 0, stream>>>(W_cq, Wt, H_, QLR);
    gemm_bt_mfma_k<float><<<dim3(QLR / 128, M / 128), blk, 0, stream>>>(xb, Wt, cq, M, QLR, H_);
    layernorm_cast_k<<<dim3(M), blk, 0, stream>>>(cq, qn_w, qn_b, cqb, QLR);

    // qp = qc @ W_q
    transpose_cast_k<<<dim3(3072 / 32, QLR / 32), blk, 0, stream>>>(W_q, Wt, QLR, 3072);
    gemm_bt_mfma_k<bf16><<<dim3(3072 / 128, M / 128), blk, 0, stream>>>(cqb, Wt, qp, M, 3072, QLR);

    // kvc = x @ W_ckv
    transpose_cast_k<<<dim3(3072 / 32, H_ / 32), blk, 0, stream>>>(W_ckv, Wt, H_, 3072);
    gemm_bt_mfma_k<bf16><<<dim3(3072 / 128, M / 128), blk, 0, stream>>>(xb, Wt, kvc, M, 3072, H_);

    // ist = x @ W_ip (fp32 out for sparse branch)
    transpose_cast_k<<<dim3(1024 / 32, H_ / 32), blk, 0, stream>>>(W_ip, Wt, H_, 1024);
    gemm_bt_mfma_k<float><<<dim3(1024 / 128, M / 128), blk, 0, stream>>>(xb, Wt, ist, M, IH * ID, H_);

    // gate = x @ W_ig — EXACT fp32 (top-k index stability)
    gate_k<<<dim3(M / 4), blk, 0, stream>>>(x, W_ig, gate);

    q_rope_k<<<dim3(2048), blk, 0, stream>>>(qp);

    // KV path: LN+RoPE (wave-per-row) -> bf16 kvn; then MFMA matmul w/ scatter.
    kv_ln_k<<<dim3(B_ * S_ * NH / 4), blk, 0, stream>>>(kvc, kvn_w, kvn_b, kvn);

    sparse_k<<<dim3(B_ * IH), blk, 0, stream>>>(gate, ist, W_sq, W_sk, W_sv, W_io, iob);

    // Wkv^T (128x256 fp32 -> 256x128 bf16) into dead gate buffer
    transpose_cast_k<<<dim3(256 / 32, 128 / 32), blk, 0, stream>>>(W_kv, WkvT, 128, 256);
    gemm_kv_k<<<dim3(2, (B_ * S_ * NH) / 128), blk, 0, stream>>>(kvn, WkvT, kvc, VbT);

    // attention -> bf16 attn (rbig; ist/kvn already consumed)
    attn_mfma_k<<<dim3(16, NH, B_), blk, 0, stream>>>(qp, kvc, VbT, iob, attnb);

    // out = attn @ W_o (VbT dead -> reuse for W_o^T)
    transpose_cast_k<<<dim3(H_ / 32, H_ / 32), blk, 0, stream>>>(W_o, Wt, H_, H_);
    gemm_bt_mfma_k<float><<<dim3(H_ / 128, M / 128), blk, 0, stream>>>(attnb, Wt, out, M, H_, H_);
}

// Round 7
// 691.768 us; speedup vs baseline: 1.0280x; 1.0280x over previous
//
#include <hip/hip_runtime.h>
#include <hip/hip_bf16.h>
#include <math.h>

// Problem constants
#define NH    16
#define NOPE  128
#define ROPED 64
#define VD    128
#define QLR   1536
#define IH    8
#define ID    128
#define TOPK  8
#define EPSF  1e-5f
#define B_    2
#define S_    2048
#define H_    2048

using bf16 = __hip_bfloat16;
typedef __attribute__((ext_vector_type(8))) short short8;
typedef __attribute__((ext_vector_type(4))) short short4v;
typedef __attribute__((ext_vector_type(4))) float f32x4;

#define GLOBAL_AS __attribute__((address_space(1)))
#define LDS_AS    __attribute__((address_space(3)))

__device__ __forceinline__ float b2f(bf16 v) { return __bfloat162float(v); }
__device__ __forceinline__ bf16 f2b(float v) { return __float2bfloat16(v); }
__device__ __forceinline__ void stoC(float* p, float v) { *p = v; }
__device__ __forceinline__ void stoC(bf16* p, float v) { *p = __float2bfloat16(v); }

// ---------------------------------------------------------------------------
// Dedicated gate projection (exact fp32, verified R4).
// ---------------------------------------------------------------------------
__global__ __launch_bounds__(256) void gate_k(const float* __restrict__ x,
                                              const float* __restrict__ Wg,
                                              float* __restrict__ gate) {
    const int t = threadIdx.x;
    const int wid = t >> 6, lane = t & 63;
    const int row = blockIdx.x * 4 + wid;
    const float* xp = x + (size_t)row * H_;

    float acc[8] = {};
    for (int k0 = 0; k0 < H_; k0 += 256) {
        const int kb = k0 + lane * 4;
        const f32x4 xv = *(const f32x4*)(xp + kb);
        const f32x4 w0 = *(const f32x4*)(Wg + (size_t)kb * 8);
        const f32x4 w1 = *(const f32x4*)(Wg + (size_t)kb * 8 + 4);
        const f32x4 w2 = *(const f32x4*)(Wg + (size_t)(kb + 1) * 8);
        const f32x4 w3 = *(const f32x4*)(Wg + (size_t)(kb + 1) * 8 + 4);
        const f32x4 w4 = *(const f32x4*)(Wg + (size_t)(kb + 2) * 8);
        const f32x4 w5 = *(const f32x4*)(Wg + (size_t)(kb + 2) * 8 + 4);
        const f32x4 w6 = *(const f32x4*)(Wg + (size_t)(kb + 3) * 8);
        const f32x4 w7 = *(const f32x4*)(Wg + (size_t)(kb + 3) * 8 + 4);
#pragma unroll
        for (int j = 0; j < 4; j++) {
            acc[j]     += xv[0] * w0[j] + xv[1] * w2[j] + xv[2] * w4[j] + xv[3] * w6[j];
            acc[4 + j] += xv[0] * w1[j] + xv[1] * w3[j] + xv[2] * w5[j] + xv[3] * w7[j];
        }
    }
#pragma unroll
    for (int j = 0; j < 8; j++) {
#pragma unroll
        for (int off = 32; off > 0; off >>= 1)
            acc[j] += __shfl_xor(acc[j], off);
    }
    if (lane == 0) {
#pragma unroll
        for (int j = 0; j < 8; j++) gate[(size_t)row * 8 + j] = acc[j];
    }
}

// ---------------------------------------------------------------------------
// bf16 MFMA GEMM, m97 structure + bijective chunked XCD swizzle.
// ---------------------------------------------------------------------------
template <typename OT>
__global__ __launch_bounds__(256) void gemm_bt_mfma_k(const bf16* __restrict__ A,
                                                      const bf16* __restrict__ Bt,
                                                      OT* __restrict__ C,
                                                      int M, int N, int K) {
    __shared__ bf16 As[128 * 32];
    __shared__ bf16 Bs[128 * 32];
    const int t = threadIdx.x;
    const int w = t >> 6;
    const int l = t & 63;
    const int col = l & 15;
    const int quad = l >> 4;
    const int wm = w >> 1, wn = w & 1;

    const int gx = gridDim.x;
    const int nwg = gx * gridDim.y;
    const int lin = blockIdx.y * gx + blockIdx.x;
    const int work = (lin & 7) * (nwg >> 3) + (lin >> 3);
    const int row0 = (work / gx) * 128;
    const int col0 = (work % gx) * 128;

    const int rA = l >> 2;
    const int cA = (l & 3) * 8;
    const bf16* ga0 = A + (size_t)(row0 + w * 16 + rA) * K + cA;
    const bf16* ga1 = A + (size_t)(row0 + (4 + w) * 16 + rA) * K + cA;
    const bf16* gb0 = Bt + (size_t)(col0 + w * 16 + rA) * K + cA;
    const bf16* gb1 = Bt + (size_t)(col0 + (4 + w) * 16 + rA) * K + cA;
    bf16* lA0 = &As[w * 512];
    bf16* lA1 = &As[(4 + w) * 512];
    bf16* lB0 = &Bs[w * 512];
    bf16* lB1 = &Bs[(4 + w) * 512];

    f32x4 acc[4][4];
#pragma unroll
    for (int i = 0; i < 4; i++)
#pragma unroll
        for (int j = 0; j < 4; j++) acc[i][j] = (f32x4){0.f, 0.f, 0.f, 0.f};

    for (int k0 = 0; k0 < K; k0 += 32) {
        __syncthreads();
        __builtin_amdgcn_global_load_lds((const GLOBAL_AS void*)(ga0 + k0),
                                         (LDS_AS void*)lA0, 16, 0, 0);
        __builtin_amdgcn_global_load_lds((const GLOBAL_AS void*)(ga1 + k0),
                                         (LDS_AS void*)lA1, 16, 0, 0);
        __builtin_amdgcn_global_load_lds((const GLOBAL_AS void*)(gb0 + k0),
                                         (LDS_AS void*)lB0, 16, 0, 0);
        __builtin_amdgcn_global_load_lds((const GLOBAL_AS void*)(gb1 + k0),
                                         (LDS_AS void*)lB1, 16, 0, 0);
        __syncthreads();

        short8 af[4], bfr[4];
#pragma unroll
        for (int i = 0; i < 4; i++) {
            af[i]  = *(const short8*)&As[(wm * 64 + i * 16 + col) * 32 + quad * 8];
            bfr[i] = *(const short8*)&Bs[(wn * 64 + i * 16 + col) * 32 + quad * 8];
        }
#pragma unroll
        for (int i = 0; i < 4; i++)
#pragma unroll
            for (int j = 0; j < 4; j++)
                acc[i][j] = __builtin_amdgcn_mfma_f32_16x16x32_bf16(af[i], bfr[j], acc[i][j], 0, 0, 0);
    }

#pragma unroll
    for (int i = 0; i < 4; i++)
#pragma unroll
        for (int j = 0; j < 4; j++)
#pragma unroll
            for (int r = 0; r < 4; r++) {
                const int gr = row0 + wm * 64 + i * 16 + quad * 4 + r;
                const int gc = col0 + wn * 64 + j * 16 + col;
                stoC(C + (size_t)gr * N + gc, acc[i][j][r]);
            }
}

// ---------------------------------------------------------------------------
// kv matmul on MFMA (verified R5). col-block 0 -> kvc k_nope; col-block 1 ->
// VbT[bh][dv][s] packed 8B stores.
// ---------------------------------------------------------------------------
__global__ __launch_bounds__(256) void gemm_kv_k(const bf16* __restrict__ A,
                                                 const bf16* __restrict__ Bt,
                                                 bf16* __restrict__ kvc,
                                                 bf16* __restrict__ VbT) {
    __shared__ bf16 As[128 * 32];
    __shared__ bf16 Bs[128 * 32];
    const int K = 128;
    const int t = threadIdx.x;
    const int w = t >> 6;
    const int l = t & 63;
    const int col = l & 15;
    const int quad = l >> 4;
    const int wm = w >> 1, wn = w & 1;

    const int gx = gridDim.x;
    const int nwg = gx * gridDim.y;
    const int lin = blockIdx.y * gx + blockIdx.x;
    const int work = (lin & 7) * (nwg >> 3) + (lin >> 3);
    const int row0 = (work / gx) * 128;
    const int col0 = (work % gx) * 128;

    const int rA = l >> 2;
    const int cA = (l & 3) * 8;
    const bf16* ga0 = A + (size_t)(row0 + w * 16 + rA) * K + cA;
    const bf16* ga1 = A + (size_t)(row0 + (4 + w) * 16 + rA) * K + cA;
    const bf16* gb0 = Bt + (size_t)(col0 + w * 16 + rA) * K + cA;
    const bf16* gb1 = Bt + (size_t)(col0 + (4 + w) * 16 + rA) * K + cA;
    bf16* lA0 = &As[w * 512];
    bf16* lA1 = &As[(4 + w) * 512];
    bf16* lB0 = &Bs[w * 512];
    bf16* lB1 = &Bs[(4 + w) * 512];

    f32x4 acc[4][4];
#pragma unroll
    for (int i = 0; i < 4; i++)
#pragma unroll
        for (int j = 0; j < 4; j++) acc[i][j] = (f32x4){0.f, 0.f, 0.f, 0.f};

    for (int k0 = 0; k0 < K; k0 += 32) {
        __syncthreads();
        __builtin_amdgcn_global_load_lds((const GLOBAL_AS void*)(ga0 + k0),
                                         (LDS_AS void*)lA0, 16, 0, 0);
        __builtin_amdgcn_global_load_lds((const GLOBAL_AS void*)(ga1 + k0),
                                         (LDS_AS void*)lA1, 16, 0, 0);
        __builtin_amdgcn_global_load_lds((const GLOBAL_AS void*)(gb0 + k0),
                                         (LDS_AS void*)lB0, 16, 0, 0);
        __builtin_amdgcn_global_load_lds((const GLOBAL_AS void*)(gb1 + k0),
                                         (LDS_AS void*)lB1, 16, 0, 0);
        __syncthreads();

        short8 af[4], bfr[4];
#pragma unroll
        for (int i = 0; i < 4; i++) {
            af[i]  = *(const short8*)&As[(wm * 64 + i * 16 + col) * 32 + quad * 8];
            bfr[i] = *(const short8*)&Bs[(wn * 64 + i * 16 + col) * 32 + quad * 8];
        }
#pragma unroll
        for (int i = 0; i < 4; i++)
#pragma unroll
            for (int j = 0; j < 4; j++)
                acc[i][j] = __builtin_amdgcn_mfma_f32_16x16x32_bf16(af[i], bfr[j], acc[i][j], 0, 0, 0);
    }

    if (col0 == 0) {
#pragma unroll
        for (int i = 0; i < 4; i++)
#pragma unroll
            for (int j = 0; j < 4; j++)
#pragma unroll
                for (int r = 0; r < 4; r++) {
                    const int gr = row0 + wm * 64 + i * 16 + quad * 4 + r;
                    const int gc = wn * 64 + j * 16 + col;
                    kvc[(size_t)gr * 192 + gc] = f2b(acc[i][j][r]);
                }
    } else {
        const int bb = row0 >> 15;
        const int ssb = ((row0 >> 4) & (S_ - 1)) + wm * 4;
#pragma unroll
        for (int j = 0; j < 4; j++) {
            const int dv = wn * 64 + j * 16 + col;
#pragma unroll
            for (int r = 0; r < 4; r++) {
                const int hh = quad * 4 + r;
                short4v pk;
#pragma unroll
                for (int i = 0; i < 4; i++) {
                    bf16 v = f2b(acc[i][j][r]);
                    pk[i] = *(short*)&v;
                }
                *(short4v*)&VbT[((size_t)(bb * NH + hh) * 128 + dv) * S_ + ssb] = pk;
            }
        }
    }
}

// ---------------------------------------------------------------------------
// Wave-per-row LN of kv_nope -> bf16 kvn, plus RoPE of k_pe.
// ---------------------------------------------------------------------------
__global__ __launch_bounds__(256) void kv_ln_k(bf16* __restrict__ kvc,
                                               const float* __restrict__ knw,
                                               const float* __restrict__ knb,
                                               bf16* __restrict__ kvn) {
    const int idx = blockIdx.x * 4 + (threadIdx.x >> 6);   // row 0..65535
    const int lane = threadIdx.x & 63;
    const int s = (idx >> 4) & (S_ - 1);
    const size_t base = (size_t)idx * 192;

    const float v0 = b2f(kvc[base + 64 + lane]);
    const float v1 = b2f(kvc[base + 128 + lane]);
    float xr = 0.f, xi = 0.f;
    if (lane < 32) { xr = b2f(kvc[base + 2 * lane]); xi = b2f(kvc[base + 2 * lane + 1]); }

    float s1 = v0 + v1, s2 = v0 * v0 + v1 * v1;
#pragma unroll
    for (int off = 32; off > 0; off >>= 1) {
        s1 += __shfl_xor(s1, off);
        s2 += __shfl_xor(s2, off);
    }
    const float mu = s1 * (1.f / 128.f);
    const float rinv = rsqrtf(s2 * (1.f / 128.f) - mu * mu + EPSF);
    kvn[(size_t)idx * 128 + lane]      = f2b((v0 - mu) * rinv * knw[lane] + knb[lane]);
    kvn[(size_t)idx * 128 + lane + 64] = f2b((v1 - mu) * rinv * knw[lane + 64] + knb[lane + 64]);

    if (lane < 32) {
        const float freq = exp2f(-0.41524101186092014f * (float)lane); // 10000^(-2l/64)
        const float ang = (float)s * freq;
        float sn, c; sincosf(ang, &sn, &c);
        kvc[base + 128 + 2 * lane]     = f2b(xr * c - xi * sn);
        kvc[base + 128 + 2 * lane + 1] = f2b(xr * sn + xi * c);
    }
}

// ---------------------------------------------------------------------------
// Elementwise fp32 -> bf16 cast.
// ---------------------------------------------------------------------------
__global__ __launch_bounds__(256) void cast_bf16_k(const float* __restrict__ X,
                                                   bf16* __restrict__ Y, int n4) {
    for (int i = blockIdx.x * 256 + threadIdx.x; i < n4; i += gridDim.x * 256) {
        const f32x4 v = ((const f32x4*)X)[i];
        short4v o;
#pragma unroll
        for (int j = 0; j < 4; j++) {
            bf16 b = f2b(v[j]);
            o[j] = *(short*)&b;
        }
        ((short4v*)Y)[i] = o;
    }
}

// ---------------------------------------------------------------------------
// Tiled transpose-cast: W (KxN fp32) -> Wt (NxK bf16).
// ---------------------------------------------------------------------------
__global__ __launch_bounds__(256) void transpose_cast_k(const float* __restrict__ W,
                                                        bf16* __restrict__ Wt,
                                                        int K, int N) {
    __shared__ float tile[32][33];
    const int t = threadIdx.x;
    const int tx = t & 31, ty = t >> 5;
    const int n0 = blockIdx.x * 32;
    const int k0 = blockIdx.y * 32;
#pragma unroll
    for (int i = 0; i < 4; i++)
        tile[ty + 8 * i][tx] = W[(size_t)(k0 + ty + 8 * i) * N + n0 + tx];
    __syncthreads();
#pragma unroll
    for (int i = 0; i < 4; i++)
        Wt[(size_t)(n0 + ty + 8 * i) * K + k0 + tx] = f2b(tile[tx][ty + 8 * i]);
}

// ---------------------------------------------------------------------------
// Row layernorm emitting bf16.
// ---------------------------------------------------------------------------
__global__ __launch_bounds__(256) void layernorm_cast_k(const float* __restrict__ X,
                                                        const float* __restrict__ w,
                                                        const float* __restrict__ b,
                                                        bf16* __restrict__ Y,
                                                        int L) {
    __shared__ float r1[256], r2[256];
    const int row = blockIdx.x;
    const int t = threadIdx.x;
    const float* xp = X + (size_t)row * L;
    bf16* yp = Y + (size_t)row * L;
    float s1 = 0.f, s2 = 0.f;
    for (int j = t; j < L; j += 256) { const float v = xp[j]; s1 += v; s2 += v * v; }
    r1[t] = s1; r2[t] = s2; __syncthreads();
    for (int off = 128; off > 0; off >>= 1) {
        if (t < off) { r1[t] += r1[t + off]; r2[t] += r2[t + off]; }
        __syncthreads();
    }
    const float mu   = r1[0] / (float)L;
    const float var  = r2[0] / (float)L - mu * mu;
    const float rinv = rsqrtf(var + EPSF);
    for (int j = t; j < L; j += 256)
        yp[j] = f2b((xp[j] - mu) * rinv * w[j] + b[j]);
}

// ---------------------------------------------------------------------------
// In-place RoPE on qp.
// ---------------------------------------------------------------------------
__global__ __launch_bounds__(256) void q_rope_k(bf16* __restrict__ qp) {
    const int total = B_ * S_ * NH * 32;
    for (int p = blockIdx.x * 256 + threadIdx.x; p < total; p += gridDim.x * 256) {
        const int j = p & 31;
        const int row = p >> 5;
        const int sr = row >> 4;
        const int s = sr & (S_ - 1);
        const size_t base = (size_t)row * 192 + 128 + 2 * j;
        const float xr = b2f(qp[base]);
        const float xi = b2f(qp[base + 1]);
        const float freq = exp2f(-0.41524101186092014f * (float)j); // 10000^(-2j/64)
        const float ang = (float)s * freq;
        float sn, c; sincosf(ang, &sn, &c);
        qp[base]     = f2b(xr * c - xi * sn);
        qp[base + 1] = f2b(xr * sn + xi * c);
    }
}

// ---------------------------------------------------------------------------
// Sparse branch (unchanged).
// ---------------------------------------------------------------------------
__global__ __launch_bounds__(256) void sparse_k(const float* __restrict__ gate,
                                                const float* __restrict__ ist,
                                                const float* __restrict__ Wsq,
                                                const float* __restrict__ Wsk,
                                                const float* __restrict__ Wsv,
                                                const float* __restrict__ Wio,
                                                float* __restrict__ io) {
    __shared__ float g[S_];
    __shared__ float sel[TOPK][ID];
    __shared__ float sq[TOPK][ID], sk[TOPK][ID], sv[TOPK][ID];
    __shared__ float sp[TOPK][TOPK];
    __shared__ float ms[ID];
    __shared__ float rv[256];
    __shared__ int ri[256];
    __shared__ int sidx[TOPK];
    const int bi = blockIdx.x;
    const int ih = bi % IH;
    const int b = bi / IH;
    const int t = threadIdx.x;

    for (int s = t; s < S_; s += 256) g[s] = gate[(size_t)(b * S_ + s) * IH + ih];
    __syncthreads();

    for (int r = 0; r < TOPK; r++) {
        float bv = -INFINITY; int bx = S_;
        for (int s = t; s < S_; s += 256) {
            const float v = g[s];
            if (v > bv) { bv = v; bx = s; }
        }
        rv[t] = bv; ri[t] = bx; __syncthreads();
        for (int off = 128; off > 0; off >>= 1) {
            if (t < off) {
                const float v2 = rv[t + off]; const int i2 = ri[t + off];
                if (v2 > rv[t] || (v2 == rv[t] && i2 < ri[t])) { rv[t] = v2; ri[t] = i2; }
            }
            __syncthreads();
        }
        if (t == 0) { sidx[r] = ri[0]; g[ri[0]] = -INFINITY; }
        __syncthreads();
    }

    for (int i = t; i < TOPK * ID; i += 256) {
        const int r = i >> 7, d = i & 127;
        sel[r][d] = ist[((size_t)(b * S_ + sidx[r]) * IH + ih) * ID + d];
    }
    __syncthreads();

    for (int i = t; i < TOPK * ID; i += 256) {
        const int r = i >> 7, n = i & 127;
        float aq = 0.f, ak = 0.f, av = 0.f;
        for (int k = 0; k < 128; k++) {
            const float s = sel[r][k];
            aq += s * Wsq[k * ID + n];
            ak += s * Wsk[k * ID + n];
            av += s * Wsv[k * ID + n];
        }
        sq[r][n] = aq; sk[r][n] = ak; sv[r][n] = av;
    }
    __syncthreads();

    if (t < TOPK * TOPK) {
        const int r = t >> 3, c = t & 7;
        float a = 0.f;
        for (int k = 0; k < 128; k++) a += sq[r][k] * sk[c][k];
        sp[r][c] = a * 0.08838834764831845f;
    }
    __syncthreads();

    if (t < TOPK) {
        float m = -INFINITY;
        for (int c = 0; c < 8; c++) m = fmaxf(m, sp[t][c]);
        float e[8]; float sum = 0.f;
        for (int c = 0; c < 8; c++) { e[c] = expf(sp[t][c] - m); sum += e[c]; }
        for (int c = 0; c < 8; c++) sp[t][c] = e[c] / sum;
    }
    __syncthreads();

    if (t < ID) {
        float acc = 0.f;
        for (int r = 0; r < 8; r++) {
            float so = 0.f;
            for (int c = 0; c < 8; c++) so += sp[r][c] * sv[c][t];
            acc += so;
        }
        ms[t] = acc * 0.125f;
    }
    __syncthreads();

    if (t < ID) {
        float acc = 0.f;
        for (int k = 0; k < 128; k++) acc += ms[k] * Wio[(size_t)k * H_ + t];
        io[((size_t)b * IH + ih) * ID + t] = acc;
    }
}

// ---------------------------------------------------------------------------
// MFMA flash attention v5 = R6 structure with the spill poison removed:
// __launch_bounds__(256, 2) (was (256,3), which capped VGPR below the
// pipeline's staging registers -> scratch spills, +45 MB HBM traffic).
// Grid is 512 blocks = 2 blocks/CU = 2 waves/SIMD; cap 256 VGPR => no spill.
// ---------------------------------------------------------------------------
__global__ __launch_bounds__(256, 2) void attn_mfma_k(const bf16* __restrict__ Qp,
                                                      const bf16* __restrict__ Kc,
                                                      const bf16* __restrict__ VbT,
                                                      const float* __restrict__ io,
                                                      bf16* __restrict__ O) {
    __shared__ unsigned short Kt[64 * 200];    // 64 keys x 192 dims (+8 pad)
    __shared__ unsigned short Vt[128 * 72];    // V^T: 128 dv x 64 keys (+8 pad)
    __shared__ unsigned short Ps[4 * 16 * 72]; // per-wave P patch 16q x 64k (+8)

    // Chunked XCD swizzle (bijective: 512 = 8 * 64)
    const int lin = blockIdx.x + 16 * blockIdx.y + 256 * blockIdx.z;
    const int swz = (lin & 7) * 64 + (lin >> 3);
    const int pairi = swz & 15;
    const int h = (swz >> 4) & 15;
    const int b = swz >> 8;

    const int t = threadIdx.x;
    const int lane = t & 63;
    const int wq = t >> 6;
    const int col = lane & 15;
    const int quad = lane >> 4;

    const float scale = 0.07216878364870322f;  // 1/sqrt(192)
    const bf16* vplane = VbT + (size_t)(b * NH + h) * 128 * (size_t)S_;

    // Staging source/dest geometry (fixed per thread)
    const int kr = t >> 2;                 // K row 0..63
    const int kc0 = (t & 3) * 48;          // K col chunk
    const int vki0 = (t & 7) * 8;          // V ki chunk
    const int vdv = t >> 3;                // V dv base (0..31), +32p

#pragma unroll 1
    for (int ti = 0; ti < 2; ti++) {
        const int qt = (ti == 0) ? pairi : 31 - pairi;
        const int q0 = qt * 64;

        short8 qfrag[6];
        {
            const int q = q0 + wq * 16 + col;
            const short8* qrow = (const short8*)(Qp + ((size_t)(b * S_ + q) * NH + h) * 192);
#pragma unroll
            for (int kc = 0; kc < 6; kc++) qfrag[kc] = qrow[kc * 4 + quad];
        }

        float m_r[4], l_r[4];
#pragma unroll
        for (int r = 0; r < 4; r++) { m_r[r] = -1e30f; l_r[r] = 0.f; }
        f32x4 accO[8];
#pragma unroll
        for (int nt = 0; nt < 8; nt++) accO[nt] = (f32x4){0.f, 0.f, 0.f, 0.f};

        const int nkt = qt + 1;

        // Prologue: load tile 0 into registers
        short8 kreg[6], vreg[4];
        {
            const short8* ksrc = (const short8*)(Kc + ((size_t)(b * S_ + kr) * NH + h) * 192 + kc0);
#pragma unroll
            for (int c = 0; c < 6; c++) kreg[c] = ksrc[c];
#pragma unroll
            for (int p = 0; p < 4; p++)
                vreg[p] = *(const short8*)(vplane + (size_t)(p * 32 + vdv) * S_ + vki0);
        }

        for (int kt = 0; kt < nkt; kt++) {
            const int kt0 = kt * 64;
            __syncthreads();   // previous tile's LDS readers done
            // Commit staged registers to LDS
            {
                short8* dst = (short8*)&Kt[kr * 200 + kc0];
#pragma unroll
                for (int c = 0; c < 6; c++) dst[c] = kreg[c];
#pragma unroll
                for (int p = 0; p < 4; p++)
                    *(short8*)&Vt[(p * 32 + vdv) * 72 + vki0] = vreg[p];
            }
            __syncthreads();   // tile ready

            // Issue next tile's global loads (latency hides under compute)
            if (kt + 1 < nkt) {
                const int nk0 = kt0 + 64;
                const short8* ksrc = (const short8*)(Kc + ((size_t)(b * S_ + nk0 + kr) * NH + h) * 192 + kc0);
#pragma unroll
                for (int c = 0; c < 6; c++) kreg[c] = ksrc[c];
#pragma unroll
                for (int p = 0; p < 4; p++)
                    vreg[p] = *(const short8*)(vplane + (size_t)(p * 32 + vdv) * S_ + nk0 + vki0);
            }

            // Scores: four 16-key n-tiles, K=192 in 6 mfma steps each.
            f32x4 s[4];
            __builtin_amdgcn_s_setprio(1);
#pragma unroll
            for (int nt = 0; nt < 4; nt++) {
                f32x4 acc = (f32x4){0.f, 0.f, 0.f, 0.f};
#pragma unroll
                for (int kc = 0; kc < 6; kc++) {
                    const short8 kf = *(const short8*)&Kt[(nt * 16 + col) * 200 + kc * 32 + quad * 8];
                    acc = __builtin_amdgcn_mfma_f32_16x16x32_bf16(qfrag[kc], kf, acc, 0, 0, 0);
                }
                s[nt] = acc;
            }
            __builtin_amdgcn_s_setprio(0);
            // Scale + causal mask
#pragma unroll
            for (int nt = 0; nt < 4; nt++)
#pragma unroll
                for (int r = 0; r < 4; r++) {
                    const int kg = kt0 + nt * 16 + col;
                    const int qg = q0 + wq * 16 + quad * 4 + r;
                    const float v = s[nt][r] * scale;
                    s[nt][r] = (kg > qg) ? -1e30f : v;
                }
            // Online softmax with defer-max (THR=8)
            float alpha[4];
#pragma unroll
            for (int r = 0; r < 4; r++) {
                float mt = fmaxf(fmaxf(s[0][r], s[1][r]), fmaxf(s[2][r], s[3][r]));
                mt = fmaxf(mt, __shfl_xor(mt, 1));
                mt = fmaxf(mt, __shfl_xor(mt, 2));
                mt = fmaxf(mt, __shfl_xor(mt, 4));
                mt = fmaxf(mt, __shfl_xor(mt, 8));
                const bool need = (mt > m_r[r] + 8.f);
                const float mn = need ? mt : m_r[r];
                alpha[r] = need ? __expf(m_r[r] - mn) : 1.f;
                m_r[r] = mn;
                float rs = 0.f;
#pragma unroll
                for (int nt = 0; nt < 4; nt++) {
                    const float p = __expf(s[nt][r] - mn);
                    s[nt][r] = p;
                    rs += p;
                }
                rs += __shfl_xor(rs, 1);
                rs += __shfl_xor(rs, 2);
                rs += __shfl_xor(rs, 4);
                rs += __shfl_xor(rs, 8);
                l_r[r] = l_r[r] * alpha[r] + rs;
            }
            // P (C-layout) -> bf16 LDS -> reread in A-layout (per-wave region).
            {
                unsigned short* pw = &Ps[wq * 1152];
#pragma unroll
                for (int nt = 0; nt < 4; nt++)
#pragma unroll
                    for (int r = 0; r < 4; r++) {
                        bf16 hv = f2b(s[nt][r]);
                        pw[(quad * 4 + r) * 72 + nt * 16 + col] = *(unsigned short*)&hv;
                    }
            }
            short8 pf[2];
#pragma unroll
            for (int kk = 0; kk < 2; kk++)
                pf[kk] = *(const short8*)&Ps[wq * 1152 + col * 72 + kk * 32 + quad * 8];
            // Rescale O only when some row actually moved its max
            if (!(alpha[0] == 1.f && alpha[1] == 1.f && alpha[2] == 1.f && alpha[3] == 1.f)) {
#pragma unroll
                for (int nt = 0; nt < 8; nt++)
#pragma unroll
                    for (int r = 0; r < 4; r++) accO[nt][r] *= alpha[r];
            }
            __builtin_amdgcn_s_setprio(1);
#pragma unroll
            for (int nt = 0; nt < 8; nt++) {
#pragma unroll
                for (int kk = 0; kk < 2; kk++) {
                    const short8 vf = *(const short8*)&Vt[(nt * 16 + col) * 72 + kk * 32 + quad * 8];
                    accO[nt] = __builtin_amdgcn_mfma_f32_16x16x32_bf16(pf[kk], vf, accO[nt], 0, 0, 0);
                }
            }
            __builtin_amdgcn_s_setprio(0);
        }

        // Epilogue (io read direct from global; 8 KB, L2-hot)
        const float* iorow = io + ((size_t)b * IH + (h >> 1)) * ID;
        float rinv[4];
#pragma unroll
        for (int r = 0; r < 4; r++) rinv[r] = 1.f / l_r[r];
#pragma unroll
        for (int nt = 0; nt < 8; nt++) {
            const int dv = nt * 16 + col;
            const float iov = iorow[dv];
#pragma unroll
            for (int r = 0; r < 4; r++) {
                const int q = q0 + wq * 16 + quad * 4 + r;
                O[((size_t)(b * S_ + q) * NH + h) * VD + dv] = f2b(accO[nt][r] * rinv[r] + iov);
            }
        }
    }
}

// ---------------------------------------------------------------------------
// Workspace lifetime plan (within proven ~100.8 MB):
//   rbig @0 (33.5MB): cq fp32 -> { ist fp32 [0,16M) ; kvn bf16 [16M,32M) }
//                      -> attnb bf16 [0,16M)
//   qp   @32MB (25.2MB)
//   kvc  @56MB (25.2MB): cq_bf16 (pre-kvc) -> kvc
//   VbT/Wt @80MB (16.8MB): Wt transposes -> VbT -> Wt(W_o)
//   gate @96MB (131KB): gate -> WkvT (64KB, post-sparse)
//   iob  @96MB+128KB
//   x_bf16 lives in d_out (dead before the final GEMM writes out).
// ---------------------------------------------------------------------------
extern "C" void kernel_launch(void* const* d_in, const int* in_sizes, int n_in,
                              void* d_out, int out_size, void* d_ws, size_t ws_size,
                              hipStream_t stream) {
    const float* x      = (const float*)d_in[0];
    const float* W_cq   = (const float*)d_in[1];
    const float* qn_w   = (const float*)d_in[2];
    const float* qn_b   = (const float*)d_in[3];
    const float* W_q    = (const float*)d_in[4];
    const float* W_ckv  = (const float*)d_in[5];
    const float* kvn_w  = (const float*)d_in[6];
    const float* kvn_b  = (const float*)d_in[7];
    const float* W_kv   = (const float*)d_in[8];
    const float* W_o    = (const float*)d_in[9];
    const float* W_ip   = (const float*)d_in[10];
    const float* W_ig   = (const float*)d_in[11];
    const float* W_sq   = (const float*)d_in[12];
    const float* W_sk   = (const float*)d_in[13];
    const float* W_sv   = (const float*)d_in[14];
    const float* W_io   = (const float*)d_in[15];
    float* out = (float*)d_out;

    const int M = B_ * S_;

    char* wsb = (char*)d_ws;
    float* rbig  = (float*)wsb;
    bf16*  kvn   = (bf16*)(wsb + 16777216);   // upper half of rbig
    bf16*  qp    = (bf16*)(wsb + 33554432);
    bf16*  kvc   = (bf16*)(wsb + 58720256);
    bf16*  cqb   = (bf16*)(wsb + 58720256);   // alias kvc (dead before kvc)
    bf16*  VbT   = (bf16*)(wsb + 83886080);
    bf16*  Wt    = (bf16*)(wsb + 83886080);   // alias VbT (disjoint lifetimes)
    float* gate  = (float*)(wsb + 100663296);
    bf16*  WkvT  = (bf16*)(wsb + 100663296);  // alias gate (post-sparse)
    float* iob   = (float*)(wsb + 100794368);
    float* cq    = rbig;
    float* ist   = rbig;
    bf16*  attnb = (bf16*)rbig;
    bf16*  xb    = (bf16*)d_out;              // x_bf16 in output buffer

    dim3 blk(256);

    // Stage 0: casts
    cast_bf16_k<<<dim3(2048), blk, 0, stream>>>(x, xb, M * H_ / 4);

    // qc = LN(x @ W_cq)
    transpose_cast_k<<<dim3(QLR / 32, H_ / 32), blk, 0, stream>>>(W_cq, Wt, H_, QLR);
    gemm_bt_mfma_k<float><<<dim3(QLR / 128, M / 128), blk, 0, stream>>>(xb, Wt, cq, M, QLR, H_);
    layernorm_cast_k<<<dim3(M), blk, 0, stream>>>(cq, qn_w, qn_b, cqb, QLR);

    // qp = qc @ W_q
    transpose_cast_k<<<dim3(3072 / 32, QLR / 32), blk, 0, stream>>>(W_q, Wt, QLR, 3072);
    gemm_bt_mfma_k<bf16><<<dim3(3072 / 128, M / 128), blk, 0, stream>>>(cqb, Wt, qp, M, 3072, QLR);

    // kvc = x @ W_ckv
    transpose_cast_k<<<dim3(3072 / 32, H_ / 32), blk, 0, stream>>>(W_ckv, Wt, H_, 3072);
    gemm_bt_mfma_k<bf16><<<dim3(3072 / 128, M / 128), blk, 0, stream>>>(xb, Wt, kvc, M, 3072, H_);

    // ist = x @ W_ip (fp32 out for sparse branch)
    transpose_cast_k<<<dim3(1024 / 32, H_ / 32), blk, 0, stream>>>(W_ip, Wt, H_, 1024);
    gemm_bt_mfma_k<float><<<dim3(1024 / 128, M / 128), blk, 0, stream>>>(xb, Wt, ist, M, IH * ID, H_);

    // gate = x @ W_ig — EXACT fp32 (top-k index stability)
    gate_k<<<dim3(M / 4), blk, 0, stream>>>(x, W_ig, gate);

    q_rope_k<<<dim3(2048), blk, 0, stream>>>(qp);

    // KV path: LN+RoPE (wave-per-row) -> bf16 kvn; then MFMA matmul w/ scatter.
    kv_ln_k<<<dim3(B_ * S_ * NH / 4), blk, 0, stream>>>(kvc, kvn_w, kvn_b, kvn);

    sparse_k<<<dim3(B_ * IH), blk, 0, stream>>>(gate, ist, W_sq, W_sk, W_sv, W_io, iob);

    // Wkv^T (128x256 fp32 -> 256x128 bf16) into dead gate buffer
    transpose_cast_k<<<dim3(256 / 32, 128 / 32), blk, 0, stream>>>(W_kv, WkvT, 128, 256);
    gemm_kv_k<<<dim3(2, (B_ * S_ * NH) / 128), blk, 0, stream>>>(kvn, WkvT, kvc, VbT);

    // attention -> bf16 attn (rbig; ist/kvn already consumed)
    attn_mfma_k<<<dim3(16, NH, B_), blk, 0, stream>>>(qp, kvc, VbT, iob, attnb);

    // out = attn @ W_o (VbT dead -> reuse for W_o^T)
    transpose_cast_k<<<dim3(H_ / 32, H_ / 32), blk, 0, stream>>>(W_o, Wt, H_, H_);
    gemm_bt_mfma_k<float><<<dim3(H_ / 128, M / 128), blk, 0, stream>>>(attnb, Wt, out, M, H_, H_);
}

// Round 8
// 678.878 us; speedup vs baseline: 1.0475x; 1.0190x over previous
//
#include <hip/hip_runtime.h>
#include <hip/hip_bf16.h>
#include <math.h>

// Problem constants
#define NH    16
#define NOPE  128
#define ROPED 64
#define VD    128
#define QLR   1536
#define IH    8
#define ID    128
#define TOPK  8
#define EPSF  1e-5f
#define B_    2
#define S_    2048
#define H_    2048

using bf16 = __hip_bfloat16;
typedef __attribute__((ext_vector_type(8))) short short8;
typedef __attribute__((ext_vector_type(4))) short short4v;
typedef __attribute__((ext_vector_type(4))) float f32x4;

#define GLOBAL_AS __attribute__((address_space(1)))
#define LDS_AS    __attribute__((address_space(3)))

__device__ __forceinline__ float b2f(bf16 v) { return __bfloat162float(v); }
__device__ __forceinline__ bf16 f2b(float v) { return __float2bfloat16(v); }
__device__ __forceinline__ void stoC(float* p, float v) { *p = v; }
__device__ __forceinline__ void stoC(bf16* p, float v) { *p = __float2bfloat16(v); }

// ---------------------------------------------------------------------------
// Dedicated gate projection (exact fp32, verified R4).
// ---------------------------------------------------------------------------
__global__ __launch_bounds__(256) void gate_k(const float* __restrict__ x,
                                              const float* __restrict__ Wg,
                                              float* __restrict__ gate) {
    const int t = threadIdx.x;
    const int wid = t >> 6, lane = t & 63;
    const int row = blockIdx.x * 4 + wid;
    const float* xp = x + (size_t)row * H_;

    float acc[8] = {};
    for (int k0 = 0; k0 < H_; k0 += 256) {
        const int kb = k0 + lane * 4;
        const f32x4 xv = *(const f32x4*)(xp + kb);
        const f32x4 w0 = *(const f32x4*)(Wg + (size_t)kb * 8);
        const f32x4 w1 = *(const f32x4*)(Wg + (size_t)kb * 8 + 4);
        const f32x4 w2 = *(const f32x4*)(Wg + (size_t)(kb + 1) * 8);
        const f32x4 w3 = *(const f32x4*)(Wg + (size_t)(kb + 1) * 8 + 4);
        const f32x4 w4 = *(const f32x4*)(Wg + (size_t)(kb + 2) * 8);
        const f32x4 w5 = *(const f32x4*)(Wg + (size_t)(kb + 2) * 8 + 4);
        const f32x4 w6 = *(const f32x4*)(Wg + (size_t)(kb + 3) * 8);
        const f32x4 w7 = *(const f32x4*)(Wg + (size_t)(kb + 3) * 8 + 4);
#pragma unroll
        for (int j = 0; j < 4; j++) {
            acc[j]     += xv[0] * w0[j] + xv[1] * w2[j] + xv[2] * w4[j] + xv[3] * w6[j];
            acc[4 + j] += xv[0] * w1[j] + xv[1] * w3[j] + xv[2] * w5[j] + xv[3] * w7[j];
        }
    }
#pragma unroll
    for (int j = 0; j < 8; j++) {
#pragma unroll
        for (int off = 32; off > 0; off >>= 1)
            acc[j] += __shfl_xor(acc[j], off);
    }
    if (lane == 0) {
#pragma unroll
        for (int j = 0; j < 8; j++) gate[(size_t)row * 8 + j] = acc[j];
    }
}

// ---------------------------------------------------------------------------
// bf16 MFMA GEMM, m97 structure + bijective chunked XCD swizzle.
// ---------------------------------------------------------------------------
template <typename OT>
__global__ __launch_bounds__(256) void gemm_bt_mfma_k(const bf16* __restrict__ A,
                                                      const bf16* __restrict__ Bt,
                                                      OT* __restrict__ C,
                                                      int M, int N, int K) {
    __shared__ bf16 As[128 * 32];
    __shared__ bf16 Bs[128 * 32];
    const int t = threadIdx.x;
    const int w = t >> 6;
    const int l = t & 63;
    const int col = l & 15;
    const int quad = l >> 4;
    const int wm = w >> 1, wn = w & 1;

    const int gx = gridDim.x;
    const int nwg = gx * gridDim.y;
    const int lin = blockIdx.y * gx + blockIdx.x;
    const int work = (lin & 7) * (nwg >> 3) + (lin >> 3);
    const int row0 = (work / gx) * 128;
    const int col0 = (work % gx) * 128;

    const int rA = l >> 2;
    const int cA = (l & 3) * 8;
    const bf16* ga0 = A + (size_t)(row0 + w * 16 + rA) * K + cA;
    const bf16* ga1 = A + (size_t)(row0 + (4 + w) * 16 + rA) * K + cA;
    const bf16* gb0 = Bt + (size_t)(col0 + w * 16 + rA) * K + cA;
    const bf16* gb1 = Bt + (size_t)(col0 + (4 + w) * 16 + rA) * K + cA;
    bf16* lA0 = &As[w * 512];
    bf16* lA1 = &As[(4 + w) * 512];
    bf16* lB0 = &Bs[w * 512];
    bf16* lB1 = &Bs[(4 + w) * 512];

    f32x4 acc[4][4];
#pragma unroll
    for (int i = 0; i < 4; i++)
#pragma unroll
        for (int j = 0; j < 4; j++) acc[i][j] = (f32x4){0.f, 0.f, 0.f, 0.f};

    for (int k0 = 0; k0 < K; k0 += 32) {
        __syncthreads();
        __builtin_amdgcn_global_load_lds((const GLOBAL_AS void*)(ga0 + k0),
                                         (LDS_AS void*)lA0, 16, 0, 0);
        __builtin_amdgcn_global_load_lds((const GLOBAL_AS void*)(ga1 + k0),
                                         (LDS_AS void*)lA1, 16, 0, 0);
        __builtin_amdgcn_global_load_lds((const GLOBAL_AS void*)(gb0 + k0),
                                         (LDS_AS void*)lB0, 16, 0, 0);
        __builtin_amdgcn_global_load_lds((const GLOBAL_AS void*)(gb1 + k0),
                                         (LDS_AS void*)lB1, 16, 0, 0);
        __syncthreads();

        short8 af[4], bfr[4];
#pragma unroll
        for (int i = 0; i < 4; i++) {
            af[i]  = *(const short8*)&As[(wm * 64 + i * 16 + col) * 32 + quad * 8];
            bfr[i] = *(const short8*)&Bs[(wn * 64 + i * 16 + col) * 32 + quad * 8];
        }
#pragma unroll
        for (int i = 0; i < 4; i++)
#pragma unroll
            for (int j = 0; j < 4; j++)
                acc[i][j] = __builtin_amdgcn_mfma_f32_16x16x32_bf16(af[i], bfr[j], acc[i][j], 0, 0, 0);
    }

#pragma unroll
    for (int i = 0; i < 4; i++)
#pragma unroll
        for (int j = 0; j < 4; j++)
#pragma unroll
            for (int r = 0; r < 4; r++) {
                const int gr = row0 + wm * 64 + i * 16 + quad * 4 + r;
                const int gc = col0 + wn * 64 + j * 16 + col;
                stoC(C + (size_t)gr * N + gc, acc[i][j][r]);
            }
}

// ---------------------------------------------------------------------------
// NEW: merged x-projection GEMM. A = xb [4096 x 2048] bf16, Bt = WtM
// [5632 x 2048] bf16 (rows: 0-1535 = W_cq^T, 1536-4607 = W_ckv^T,
// 4608-5631 = W_ip^T). Epilogue routes by col0 (block-uniform since 1536
// and 4608 are multiples of 128): cq fp32 / kvc bf16 / ist fp32.
// Grid 44 x 32 = 1408 blocks (vs 384+768+256 in three launches).
// ---------------------------------------------------------------------------
__global__ __launch_bounds__(256) void gemm_x3_k(const bf16* __restrict__ A,
                                                 const bf16* __restrict__ Bt,
                                                 float* __restrict__ cq,
                                                 bf16* __restrict__ kvc,
                                                 float* __restrict__ ist) {
    __shared__ bf16 As[128 * 32];
    __shared__ bf16 Bs[128 * 32];
    const int K = H_;
    const int t = threadIdx.x;
    const int w = t >> 6;
    const int l = t & 63;
    const int col = l & 15;
    const int quad = l >> 4;
    const int wm = w >> 1, wn = w & 1;

    const int gx = gridDim.x;
    const int nwg = gx * gridDim.y;
    const int lin = blockIdx.y * gx + blockIdx.x;
    const int work = (lin & 7) * (nwg >> 3) + (lin >> 3);
    const int row0 = (work / gx) * 128;
    const int col0 = (work % gx) * 128;

    const int rA = l >> 2;
    const int cA = (l & 3) * 8;
    const bf16* ga0 = A + (size_t)(row0 + w * 16 + rA) * K + cA;
    const bf16* ga1 = A + (size_t)(row0 + (4 + w) * 16 + rA) * K + cA;
    const bf16* gb0 = Bt + (size_t)(col0 + w * 16 + rA) * K + cA;
    const bf16* gb1 = Bt + (size_t)(col0 + (4 + w) * 16 + rA) * K + cA;
    bf16* lA0 = &As[w * 512];
    bf16* lA1 = &As[(4 + w) * 512];
    bf16* lB0 = &Bs[w * 512];
    bf16* lB1 = &Bs[(4 + w) * 512];

    f32x4 acc[4][4];
#pragma unroll
    for (int i = 0; i < 4; i++)
#pragma unroll
        for (int j = 0; j < 4; j++) acc[i][j] = (f32x4){0.f, 0.f, 0.f, 0.f};

    for (int k0 = 0; k0 < K; k0 += 32) {
        __syncthreads();
        __builtin_amdgcn_global_load_lds((const GLOBAL_AS void*)(ga0 + k0),
                                         (LDS_AS void*)lA0, 16, 0, 0);
        __builtin_amdgcn_global_load_lds((const GLOBAL_AS void*)(ga1 + k0),
                                         (LDS_AS void*)lA1, 16, 0, 0);
        __builtin_amdgcn_global_load_lds((const GLOBAL_AS void*)(gb0 + k0),
                                         (LDS_AS void*)lB0, 16, 0, 0);
        __builtin_amdgcn_global_load_lds((const GLOBAL_AS void*)(gb1 + k0),
                                         (LDS_AS void*)lB1, 16, 0, 0);
        __syncthreads();

        short8 af[4], bfr[4];
#pragma unroll
        for (int i = 0; i < 4; i++) {
            af[i]  = *(const short8*)&As[(wm * 64 + i * 16 + col) * 32 + quad * 8];
            bfr[i] = *(const short8*)&Bs[(wn * 64 + i * 16 + col) * 32 + quad * 8];
        }
#pragma unroll
        for (int i = 0; i < 4; i++)
#pragma unroll
            for (int j = 0; j < 4; j++)
                acc[i][j] = __builtin_amdgcn_mfma_f32_16x16x32_bf16(af[i], bfr[j], acc[i][j], 0, 0, 0);
    }

#pragma unroll
    for (int i = 0; i < 4; i++)
#pragma unroll
        for (int j = 0; j < 4; j++)
#pragma unroll
            for (int r = 0; r < 4; r++) {
                const int gr = row0 + wm * 64 + i * 16 + quad * 4 + r;
                const int gc = col0 + wn * 64 + j * 16 + col;
                const float v = acc[i][j][r];
                if (col0 < 1536)       cq[(size_t)gr * QLR + gc] = v;
                else if (col0 < 4608)  kvc[(size_t)gr * 3072 + (gc - 1536)] = f2b(v);
                else                   ist[(size_t)gr * 1024 + (gc - 4608)] = v;
            }
}

// ---------------------------------------------------------------------------
// kv matmul on MFMA (verified R5). col-block 0 -> kvc k_nope; col-block 1 ->
// VbT[bh][dv][s] packed 8B stores.
// ---------------------------------------------------------------------------
__global__ __launch_bounds__(256) void gemm_kv_k(const bf16* __restrict__ A,
                                                 const bf16* __restrict__ Bt,
                                                 bf16* __restrict__ kvc,
                                                 bf16* __restrict__ VbT) {
    __shared__ bf16 As[128 * 32];
    __shared__ bf16 Bs[128 * 32];
    const int K = 128;
    const int t = threadIdx.x;
    const int w = t >> 6;
    const int l = t & 63;
    const int col = l & 15;
    const int quad = l >> 4;
    const int wm = w >> 1, wn = w & 1;

    const int gx = gridDim.x;
    const int nwg = gx * gridDim.y;
    const int lin = blockIdx.y * gx + blockIdx.x;
    const int work = (lin & 7) * (nwg >> 3) + (lin >> 3);
    const int row0 = (work / gx) * 128;
    const int col0 = (work % gx) * 128;

    const int rA = l >> 2;
    const int cA = (l & 3) * 8;
    const bf16* ga0 = A + (size_t)(row0 + w * 16 + rA) * K + cA;
    const bf16* ga1 = A + (size_t)(row0 + (4 + w) * 16 + rA) * K + cA;
    const bf16* gb0 = Bt + (size_t)(col0 + w * 16 + rA) * K + cA;
    const bf16* gb1 = Bt + (size_t)(col0 + (4 + w) * 16 + rA) * K + cA;
    bf16* lA0 = &As[w * 512];
    bf16* lA1 = &As[(4 + w) * 512];
    bf16* lB0 = &Bs[w * 512];
    bf16* lB1 = &Bs[(4 + w) * 512];

    f32x4 acc[4][4];
#pragma unroll
    for (int i = 0; i < 4; i++)
#pragma unroll
        for (int j = 0; j < 4; j++) acc[i][j] = (f32x4){0.f, 0.f, 0.f, 0.f};

    for (int k0 = 0; k0 < K; k0 += 32) {
        __syncthreads();
        __builtin_amdgcn_global_load_lds((const GLOBAL_AS void*)(ga0 + k0),
                                         (LDS_AS void*)lA0, 16, 0, 0);
        __builtin_amdgcn_global_load_lds((const GLOBAL_AS void*)(ga1 + k0),
                                         (LDS_AS void*)lA1, 16, 0, 0);
        __builtin_amdgcn_global_load_lds((const GLOBAL_AS void*)(gb0 + k0),
                                         (LDS_AS void*)lB0, 16, 0, 0);
        __builtin_amdgcn_global_load_lds((const GLOBAL_AS void*)(gb1 + k0),
                                         (LDS_AS void*)lB1, 16, 0, 0);
        __syncthreads();

        short8 af[4], bfr[4];
#pragma unroll
        for (int i = 0; i < 4; i++) {
            af[i]  = *(const short8*)&As[(wm * 64 + i * 16 + col) * 32 + quad * 8];
            bfr[i] = *(const short8*)&Bs[(wn * 64 + i * 16 + col) * 32 + quad * 8];
        }
#pragma unroll
        for (int i = 0; i < 4; i++)
#pragma unroll
            for (int j = 0; j < 4; j++)
                acc[i][j] = __builtin_amdgcn_mfma_f32_16x16x32_bf16(af[i], bfr[j], acc[i][j], 0, 0, 0);
    }

    if (col0 == 0) {
#pragma unroll
        for (int i = 0; i < 4; i++)
#pragma unroll
            for (int j = 0; j < 4; j++)
#pragma unroll
                for (int r = 0; r < 4; r++) {
                    const int gr = row0 + wm * 64 + i * 16 + quad * 4 + r;
                    const int gc = wn * 64 + j * 16 + col;
                    kvc[(size_t)gr * 192 + gc] = f2b(acc[i][j][r]);
                }
    } else {
        const int bb = row0 >> 15;
        const int ssb = ((row0 >> 4) & (S_ - 1)) + wm * 4;
#pragma unroll
        for (int j = 0; j < 4; j++) {
            const int dv = wn * 64 + j * 16 + col;
#pragma unroll
            for (int r = 0; r < 4; r++) {
                const int hh = quad * 4 + r;
                short4v pk;
#pragma unroll
                for (int i = 0; i < 4; i++) {
                    bf16 v = f2b(acc[i][j][r]);
                    pk[i] = *(short*)&v;
                }
                *(short4v*)&VbT[((size_t)(bb * NH + hh) * 128 + dv) * S_ + ssb] = pk;
            }
        }
    }
}

// ---------------------------------------------------------------------------
// Wave-per-row LN of kv_nope -> bf16 kvn, plus RoPE of k_pe.
// ---------------------------------------------------------------------------
__global__ __launch_bounds__(256) void kv_ln_k(bf16* __restrict__ kvc,
                                               const float* __restrict__ knw,
                                               const float* __restrict__ knb,
                                               bf16* __restrict__ kvn) {
    const int idx = blockIdx.x * 4 + (threadIdx.x >> 6);   // row 0..65535
    const int lane = threadIdx.x & 63;
    const int s = (idx >> 4) & (S_ - 1);
    const size_t base = (size_t)idx * 192;

    const float v0 = b2f(kvc[base + 64 + lane]);
    const float v1 = b2f(kvc[base + 128 + lane]);
    float xr = 0.f, xi = 0.f;
    if (lane < 32) { xr = b2f(kvc[base + 2 * lane]); xi = b2f(kvc[base + 2 * lane + 1]); }

    float s1 = v0 + v1, s2 = v0 * v0 + v1 * v1;
#pragma unroll
    for (int off = 32; off > 0; off >>= 1) {
        s1 += __shfl_xor(s1, off);
        s2 += __shfl_xor(s2, off);
    }
    const float mu = s1 * (1.f / 128.f);
    const float rinv = rsqrtf(s2 * (1.f / 128.f) - mu * mu + EPSF);
    kvn[(size_t)idx * 128 + lane]      = f2b((v0 - mu) * rinv * knw[lane] + knb[lane]);
    kvn[(size_t)idx * 128 + lane + 64] = f2b((v1 - mu) * rinv * knw[lane + 64] + knb[lane + 64]);

    if (lane < 32) {
        const float freq = exp2f(-0.41524101186092014f * (float)lane); // 10000^(-2l/64)
        const float ang = (float)s * freq;
        float sn, c; sincosf(ang, &sn, &c);
        kvc[base + 128 + 2 * lane]     = f2b(xr * c - xi * sn);
        kvc[base + 128 + 2 * lane + 1] = f2b(xr * sn + xi * c);
    }
}

// ---------------------------------------------------------------------------
// Elementwise fp32 -> bf16 cast.
// ---------------------------------------------------------------------------
__global__ __launch_bounds__(256) void cast_bf16_k(const float* __restrict__ X,
                                                   bf16* __restrict__ Y, int n4) {
    for (int i = blockIdx.x * 256 + threadIdx.x; i < n4; i += gridDim.x * 256) {
        const f32x4 v = ((const f32x4*)X)[i];
        short4v o;
#pragma unroll
        for (int j = 0; j < 4; j++) {
            bf16 b = f2b(v[j]);
            o[j] = *(short*)&b;
        }
        ((short4v*)Y)[i] = o;
    }
}

// ---------------------------------------------------------------------------
// Tiled transpose-cast: W (KxN fp32) -> Wt (NxK bf16).
// ---------------------------------------------------------------------------
__global__ __launch_bounds__(256) void transpose_cast_k(const float* __restrict__ W,
                                                        bf16* __restrict__ Wt,
                                                        int K, int N) {
    __shared__ float tile[32][33];
    const int t = threadIdx.x;
    const int tx = t & 31, ty = t >> 5;
    const int n0 = blockIdx.x * 32;
    const int k0 = blockIdx.y * 32;
#pragma unroll
    for (int i = 0; i < 4; i++)
        tile[ty + 8 * i][tx] = W[(size_t)(k0 + ty + 8 * i) * N + n0 + tx];
    __syncthreads();
#pragma unroll
    for (int i = 0; i < 4; i++)
        Wt[(size_t)(n0 + ty + 8 * i) * K + k0 + tx] = f2b(tile[tx][ty + 8 * i]);
}

// ---------------------------------------------------------------------------
// Row layernorm emitting bf16.
// ---------------------------------------------------------------------------
__global__ __launch_bounds__(256) void layernorm_cast_k(const float* __restrict__ X,
                                                        const float* __restrict__ w,
                                                        const float* __restrict__ b,
                                                        bf16* __restrict__ Y,
                                                        int L) {
    __shared__ float r1[256], r2[256];
    const int row = blockIdx.x;
    const int t = threadIdx.x;
    const float* xp = X + (size_t)row * L;
    bf16* yp = Y + (size_t)row * L;
    float s1 = 0.f, s2 = 0.f;
    for (int j = t; j < L; j += 256) { const float v = xp[j]; s1 += v; s2 += v * v; }
    r1[t] = s1; r2[t] = s2; __syncthreads();
    for (int off = 128; off > 0; off >>= 1) {
        if (t < off) { r1[t] += r1[t + off]; r2[t] += r2[t + off]; }
        __syncthreads();
    }
    const float mu   = r1[0] / (float)L;
    const float var  = r2[0] / (float)L - mu * mu;
    const float rinv = rsqrtf(var + EPSF);
    for (int j = t; j < L; j += 256)
        yp[j] = f2b((xp[j] - mu) * rinv * w[j] + b[j]);
}

// ---------------------------------------------------------------------------
// In-place RoPE on qp.
// ---------------------------------------------------------------------------
__global__ __launch_bounds__(256) void q_rope_k(bf16* __restrict__ qp) {
    const int total = B_ * S_ * NH * 32;
    for (int p = blockIdx.x * 256 + threadIdx.x; p < total; p += gridDim.x * 256) {
        const int j = p & 31;
        const int row = p >> 5;
        const int sr = row >> 4;
        const int s = sr & (S_ - 1);
        const size_t base = (size_t)row * 192 + 128 + 2 * j;
        const float xr = b2f(qp[base]);
        const float xi = b2f(qp[base + 1]);
        const float freq = exp2f(-0.41524101186092014f * (float)j); // 10000^(-2j/64)
        const float ang = (float)s * freq;
        float sn, c; sincosf(ang, &sn, &c);
        qp[base]     = f2b(xr * c - xi * sn);
        qp[base + 1] = f2b(xr * sn + xi * c);
    }
}

// ---------------------------------------------------------------------------
// Sparse branch (unchanged).
// ---------------------------------------------------------------------------
__global__ __launch_bounds__(256) void sparse_k(const float* __restrict__ gate,
                                                const float* __restrict__ ist,
                                                const float* __restrict__ Wsq,
                                                const float* __restrict__ Wsk,
                                                const float* __restrict__ Wsv,
                                                const float* __restrict__ Wio,
                                                float* __restrict__ io) {
    __shared__ float g[S_];
    __shared__ float sel[TOPK][ID];
    __shared__ float sq[TOPK][ID], sk[TOPK][ID], sv[TOPK][ID];
    __shared__ float sp[TOPK][TOPK];
    __shared__ float ms[ID];
    __shared__ float rv[256];
    __shared__ int ri[256];
    __shared__ int sidx[TOPK];
    const int bi = blockIdx.x;
    const int ih = bi % IH;
    const int b = bi / IH;
    const int t = threadIdx.x;

    for (int s = t; s < S_; s += 256) g[s] = gate[(size_t)(b * S_ + s) * IH + ih];
    __syncthreads();

    for (int r = 0; r < TOPK; r++) {
        float bv = -INFINITY; int bx = S_;
        for (int s = t; s < S_; s += 256) {
            const float v = g[s];
            if (v > bv) { bv = v; bx = s; }
        }
        rv[t] = bv; ri[t] = bx; __syncthreads();
        for (int off = 128; off > 0; off >>= 1) {
            if (t < off) {
                const float v2 = rv[t + off]; const int i2 = ri[t + off];
                if (v2 > rv[t] || (v2 == rv[t] && i2 < ri[t])) { rv[t] = v2; ri[t] = i2; }
            }
            __syncthreads();
        }
        if (t == 0) { sidx[r] = ri[0]; g[ri[0]] = -INFINITY; }
        __syncthreads();
    }

    for (int i = t; i < TOPK * ID; i += 256) {
        const int r = i >> 7, d = i & 127;
        sel[r][d] = ist[((size_t)(b * S_ + sidx[r]) * IH + ih) * ID + d];
    }
    __syncthreads();

    for (int i = t; i < TOPK * ID; i += 256) {
        const int r = i >> 7, n = i & 127;
        float aq = 0.f, ak = 0.f, av = 0.f;
        for (int k = 0; k < 128; k++) {
            const float s = sel[r][k];
            aq += s * Wsq[k * ID + n];
            ak += s * Wsk[k * ID + n];
            av += s * Wsv[k * ID + n];
        }
        sq[r][n] = aq; sk[r][n] = ak; sv[r][n] = av;
    }
    __syncthreads();

    if (t < TOPK * TOPK) {
        const int r = t >> 3, c = t & 7;
        float a = 0.f;
        for (int k = 0; k < 128; k++) a += sq[r][k] * sk[c][k];
        sp[r][c] = a * 0.08838834764831845f;
    }
    __syncthreads();

    if (t < TOPK) {
        float m = -INFINITY;
        for (int c = 0; c < 8; c++) m = fmaxf(m, sp[t][c]);
        float e[8]; float sum = 0.f;
        for (int c = 0; c < 8; c++) { e[c] = expf(sp[t][c] - m); sum += e[c]; }
        for (int c = 0; c < 8; c++) sp[t][c] = e[c] / sum;
    }
    __syncthreads();

    if (t < ID) {
        float acc = 0.f;
        for (int r = 0; r < 8; r++) {
            float so = 0.f;
            for (int c = 0; c < 8; c++) so += sp[r][c] * sv[c][t];
            acc += so;
        }
        ms[t] = acc * 0.125f;
    }
    __syncthreads();

    if (t < ID) {
        float acc = 0.f;
        for (int k = 0; k < 128; k++) acc += ms[k] * Wio[(size_t)k * H_ + t];
        io[((size_t)b * IH + ih) * ID + t] = acc;
    }
}

// ---------------------------------------------------------------------------
// MFMA flash attention v6: one q-tile per block, HEAVY-FIRST dispatch.
// Grid 1024 blocks; lin>>5 ranks qt descending (all qt=31 blocks dispatch
// first) so the causal imbalance is absorbed by dynamic block scheduling.
// LDS 53.2 KB + VGPR 112 allow 3 blocks/CU -> 3 waves/SIMD latency hiding
// (R7 was grid-limited to 2). Pipeline staging + defer-max retained.
// ---------------------------------------------------------------------------
__global__ __launch_bounds__(256, 2) void attn_mfma_k(const bf16* __restrict__ Qp,
                                                      const bf16* __restrict__ Kc,
                                                      const bf16* __restrict__ VbT,
                                                      const float* __restrict__ io,
                                                      bf16* __restrict__ O) {
    __shared__ unsigned short Kt[64 * 200];    // 64 keys x 192 dims (+8 pad)
    __shared__ unsigned short Vt[128 * 72];    // V^T: 128 dv x 64 keys (+8 pad)
    __shared__ unsigned short Ps[4 * 16 * 72]; // per-wave P patch 16q x 64k (+8)

    const int lin = blockIdx.x;
    const int qt = 31 - (lin >> 5);            // heavy-first
    const int hb = lin & 31;
    const int h = hb & 15;
    const int b = hb >> 4;
    const int q0 = qt * 64;

    const int t = threadIdx.x;
    const int lane = t & 63;
    const int wq = t >> 6;
    const int col = lane & 15;
    const int quad = lane >> 4;

    const float scale = 0.07216878364870322f;  // 1/sqrt(192)
    const bf16* vplane = VbT + (size_t)(b * NH + h) * 128 * (size_t)S_;

    // Staging source/dest geometry (fixed per thread)
    const int kr = t >> 2;                 // K row 0..63
    const int kc0 = (t & 3) * 48;          // K col chunk
    const int vki0 = (t & 7) * 8;          // V ki chunk
    const int vdv = t >> 3;                // V dv base (0..31), +32p

    short8 qfrag[6];
    {
        const int q = q0 + wq * 16 + col;
        const short8* qrow = (const short8*)(Qp + ((size_t)(b * S_ + q) * NH + h) * 192);
#pragma unroll
        for (int kc = 0; kc < 6; kc++) qfrag[kc] = qrow[kc * 4 + quad];
    }

    float m_r[4], l_r[4];
#pragma unroll
    for (int r = 0; r < 4; r++) { m_r[r] = -1e30f; l_r[r] = 0.f; }
    f32x4 accO[8];
#pragma unroll
    for (int nt = 0; nt < 8; nt++) accO[nt] = (f32x4){0.f, 0.f, 0.f, 0.f};

    const int nkt = qt + 1;

    // Prologue: load tile 0 into registers
    short8 kreg[6], vreg[4];
    {
        const short8* ksrc = (const short8*)(Kc + ((size_t)(b * S_ + kr) * NH + h) * 192 + kc0);
#pragma unroll
        for (int c = 0; c < 6; c++) kreg[c] = ksrc[c];
#pragma unroll
        for (int p = 0; p < 4; p++)
            vreg[p] = *(const short8*)(vplane + (size_t)(p * 32 + vdv) * S_ + vki0);
    }

    for (int kt = 0; kt < nkt; kt++) {
        const int kt0 = kt * 64;
        __syncthreads();   // previous tile's LDS readers done
        // Commit staged registers to LDS
        {
            short8* dst = (short8*)&Kt[kr * 200 + kc0];
#pragma unroll
            for (int c = 0; c < 6; c++) dst[c] = kreg[c];
#pragma unroll
            for (int p = 0; p < 4; p++)
                *(short8*)&Vt[(p * 32 + vdv) * 72 + vki0] = vreg[p];
        }
        __syncthreads();   // tile ready

        // Issue next tile's global loads (latency hides under compute)
        if (kt + 1 < nkt) {
            const int nk0 = kt0 + 64;
            const short8* ksrc = (const short8*)(Kc + ((size_t)(b * S_ + nk0 + kr) * NH + h) * 192 + kc0);
#pragma unroll
            for (int c = 0; c < 6; c++) kreg[c] = ksrc[c];
#pragma unroll
            for (int p = 0; p < 4; p++)
                vreg[p] = *(const short8*)(vplane + (size_t)(p * 32 + vdv) * S_ + nk0 + vki0);
        }

        // Scores: four 16-key n-tiles, K=192 in 6 mfma steps each.
        f32x4 s[4];
        __builtin_amdgcn_s_setprio(1);
#pragma unroll
        for (int nt = 0; nt < 4; nt++) {
            f32x4 acc = (f32x4){0.f, 0.f, 0.f, 0.f};
#pragma unroll
            for (int kc = 0; kc < 6; kc++) {
                const short8 kf = *(const short8*)&Kt[(nt * 16 + col) * 200 + kc * 32 + quad * 8];
                acc = __builtin_amdgcn_mfma_f32_16x16x32_bf16(qfrag[kc], kf, acc, 0, 0, 0);
            }
            s[nt] = acc;
        }
        __builtin_amdgcn_s_setprio(0);
        // Scale + causal mask
#pragma unroll
        for (int nt = 0; nt < 4; nt++)
#pragma unroll
            for (int r = 0; r < 4; r++) {
                const int kg = kt0 + nt * 16 + col;
                const int qg = q0 + wq * 16 + quad * 4 + r;
                const float v = s[nt][r] * scale;
                s[nt][r] = (kg > qg) ? -1e30f : v;
            }
        // Online softmax with defer-max (THR=8)
        float alpha[4];
#pragma unroll
        for (int r = 0; r < 4; r++) {
            float mt = fmaxf(fmaxf(s[0][r], s[1][r]), fmaxf(s[2][r], s[3][r]));
            mt = fmaxf(mt, __shfl_xor(mt, 1));
            mt = fmaxf(mt, __shfl_xor(mt, 2));
            mt = fmaxf(mt, __shfl_xor(mt, 4));
            mt = fmaxf(mt, __shfl_xor(mt, 8));
            const bool need = (mt > m_r[r] + 8.f);
            const float mn = need ? mt : m_r[r];
            alpha[r] = need ? __expf(m_r[r] - mn) : 1.f;
            m_r[r] = mn;
            float rs = 0.f;
#pragma unroll
            for (int nt = 0; nt < 4; nt++) {
                const float p = __expf(s[nt][r] - mn);
                s[nt][r] = p;
                rs += p;
            }
            rs += __shfl_xor(rs, 1);
            rs += __shfl_xor(rs, 2);
            rs += __shfl_xor(rs, 4);
            rs += __shfl_xor(rs, 8);
            l_r[r] = l_r[r] * alpha[r] + rs;
        }
        // P (C-layout) -> bf16 LDS -> reread in A-layout (per-wave region).
        {
            unsigned short* pw = &Ps[wq * 1152];
#pragma unroll
            for (int nt = 0; nt < 4; nt++)
#pragma unroll
                for (int r = 0; r < 4; r++) {
                    bf16 hv = f2b(s[nt][r]);
                    pw[(quad * 4 + r) * 72 + nt * 16 + col] = *(unsigned short*)&hv;
                }
        }
        short8 pf[2];
#pragma unroll
        for (int kk = 0; kk < 2; kk++)
            pf[kk] = *(const short8*)&Ps[wq * 1152 + col * 72 + kk * 32 + quad * 8];
        // Rescale O only when some row actually moved its max
        if (!(alpha[0] == 1.f && alpha[1] == 1.f && alpha[2] == 1.f && alpha[3] == 1.f)) {
#pragma unroll
            for (int nt = 0; nt < 8; nt++)
#pragma unroll
                for (int r = 0; r < 4; r++) accO[nt][r] *= alpha[r];
        }
        __builtin_amdgcn_s_setprio(1);
#pragma unroll
        for (int nt = 0; nt < 8; nt++) {
#pragma unroll
            for (int kk = 0; kk < 2; kk++) {
                const short8 vf = *(const short8*)&Vt[(nt * 16 + col) * 72 + kk * 32 + quad * 8];
                accO[nt] = __builtin_amdgcn_mfma_f32_16x16x32_bf16(pf[kk], vf, accO[nt], 0, 0, 0);
            }
        }
        __builtin_amdgcn_s_setprio(0);
    }

    // Epilogue (io read direct from global; 8 KB, L2-hot)
    const float* iorow = io + ((size_t)b * IH + (h >> 1)) * ID;
    float rinv[4];
#pragma unroll
    for (int r = 0; r < 4; r++) rinv[r] = 1.f / l_r[r];
#pragma unroll
    for (int nt = 0; nt < 8; nt++) {
        const int dv = nt * 16 + col;
        const float iov = iorow[dv];
#pragma unroll
        for (int r = 0; r < 4; r++) {
            const int q = q0 + wq * 16 + quad * 4 + r;
            O[((size_t)(b * S_ + q) * NH + h) * VD + dv] = f2b(accO[nt][r] * rinv[r] + iov);
        }
    }
}

// ---------------------------------------------------------------------------
// Workspace timeline (all slots within proven ~100.8 MB):
//  S0 = ws+0       (33.5MB): WtM(23.1) -> cqb(12.6)+WqT(9.4 @+12.6M)
//                            -> kvn(16.8) -> attnb(16.8)+WoT(8.4 @+16.8M)
//  S1 = ws+32MB    (25.2MB): cq fp32 (25.2) -> qp bf16 (25.2)
//  S2 = ws+56MB    (25.2MB): kvc
//  S3 = ws+80MB    (16.8MB): ist fp32 -> VbT
//  S4 = ws+96MB    (131KB) : gate -> WkvT
//  S5 = ws+96MB+128KB      : iob
//  xb lives in d_out (dead after gemm_x3; out written last).
// ---------------------------------------------------------------------------
extern "C" void kernel_launch(void* const* d_in, const int* in_sizes, int n_in,
                              void* d_out, int out_size, void* d_ws, size_t ws_size,
                              hipStream_t stream) {
    const float* x      = (const float*)d_in[0];
    const float* W_cq   = (const float*)d_in[1];
    const float* qn_w   = (const float*)d_in[2];
    const float* qn_b   = (const float*)d_in[3];
    const float* W_q    = (const float*)d_in[4];
    const float* W_ckv  = (const float*)d_in[5];
    const float* kvn_w  = (const float*)d_in[6];
    const float* kvn_b  = (const float*)d_in[7];
    const float* W_kv   = (const float*)d_in[8];
    const float* W_o    = (const float*)d_in[9];
    const float* W_ip   = (const float*)d_in[10];
    const float* W_ig   = (const float*)d_in[11];
    const float* W_sq   = (const float*)d_in[12];
    const float* W_sk   = (const float*)d_in[13];
    const float* W_sv   = (const float*)d_in[14];
    const float* W_io   = (const float*)d_in[15];
    float* out = (float*)d_out;

    const int M = B_ * S_;

    char* wsb = (char*)d_ws;
    // S0 tenants
    bf16*  WtM   = (bf16*)wsb;                       // merged x-proj weights^T (23.1MB)
    bf16*  cqb   = (bf16*)wsb;                       // bf16 LN output (12.6MB)
    bf16*  WqT   = (bf16*)(wsb + 12582912);          // W_q^T (9.4MB)
    bf16*  kvn   = (bf16*)wsb;                       // LN'd kv_nope (16.8MB)
    bf16*  attnb = (bf16*)wsb;                       // attention out bf16 (16.8MB)
    bf16*  WoT   = (bf16*)(wsb + 16777216);          // W_o^T (8.4MB)
    // S1
    float* cq    = (float*)(wsb + 33554432);         // fp32 qc (25.2MB)
    bf16*  qp    = (bf16*)(wsb + 33554432);          // q-proj bf16 (25.2MB)
    // S2
    bf16*  kvc   = (bf16*)(wsb + 58720256);
    // S3
    float* ist   = (float*)(wsb + 83886080);         // fp32 (16.8MB)
    bf16*  VbT   = (bf16*)(wsb + 83886080);          // transposed V (16.8MB)
    // S4/S5
    float* gate  = (float*)(wsb + 100663296);
    bf16*  WkvT  = (bf16*)(wsb + 100663296);
    float* iob   = (float*)(wsb + 100794368);
    bf16*  xb    = (bf16*)d_out;                     // x bf16 in output buffer

    dim3 blk(256);

    // 1. cast x -> bf16
    cast_bf16_k<<<dim3(2048), blk, 0, stream>>>(x, xb, M * H_ / 4);

    // 2. merged weight transposes into WtM rows [0,1536)|[1536,4608)|[4608,5632)
    transpose_cast_k<<<dim3(QLR / 32, H_ / 32), blk, 0, stream>>>(W_cq, WtM, H_, QLR);
    transpose_cast_k<<<dim3(3072 / 32, H_ / 32), blk, 0, stream>>>(W_ckv, WtM + (size_t)1536 * H_, H_, 3072);
    transpose_cast_k<<<dim3(1024 / 32, H_ / 32), blk, 0, stream>>>(W_ip, WtM + (size_t)4608 * H_, H_, 1024);

    // 3. merged GEMM: cq | kvc | ist
    gemm_x3_k<<<dim3(5632 / 128, M / 128), blk, 0, stream>>>(xb, WtM, cq, kvc, ist);

    // 4. LN -> cqb (frees WtM)
    layernorm_cast_k<<<dim3(M), blk, 0, stream>>>(cq, qn_w, qn_b, cqb, QLR);

    // 5-6. qp = cqb @ W_q (cq dead -> qp in S1)
    transpose_cast_k<<<dim3(3072 / 32, QLR / 32), blk, 0, stream>>>(W_q, WqT, QLR, 3072);
    gemm_bt_mfma_k<bf16><<<dim3(3072 / 128, M / 128), blk, 0, stream>>>(cqb, WqT, qp, M, 3072, QLR);

    // 7. gate = x @ W_ig — EXACT fp32
    gate_k<<<dim3(M / 4), blk, 0, stream>>>(x, W_ig, gate);

    // 8. RoPE q
    q_rope_k<<<dim3(2048), blk, 0, stream>>>(qp);

    // 9. kv LN (cqb/WqT dead -> kvn in S0)
    kv_ln_k<<<dim3(B_ * S_ * NH / 4), blk, 0, stream>>>(kvc, kvn_w, kvn_b, kvn);

    // 10. sparse branch (consumes ist)
    sparse_k<<<dim3(B_ * IH), blk, 0, stream>>>(gate, ist, W_sq, W_sk, W_sv, W_io, iob);

    // 11-12. kv matmul (gate dead -> WkvT; ist dead -> VbT)
    transpose_cast_k<<<dim3(256 / 32, 128 / 32), blk, 0, stream>>>(W_kv, WkvT, 128, 256);
    gemm_kv_k<<<dim3(2, (B_ * S_ * NH) / 128), blk, 0, stream>>>(kvn, WkvT, kvc, VbT);

    // 13. attention, heavy-first single-tile grid (kvn dead -> attnb in S0)
    attn_mfma_k<<<dim3(1024), blk, 0, stream>>>(qp, kvc, VbT, iob, attnb);

    // 14-15. out = attnb @ W_o (VbT dead; WoT at S0+16.8M, disjoint from attnb)
    transpose_cast_k<<<dim3(H_ / 32, H_ / 32), blk, 0, stream>>>(W_o, WoT, H_, H_);
    gemm_bt_mfma_k<float><<<dim3(H_ / 128, M / 128), blk, 0, stream>>>(attnb, WoT, out, M, H_, H_);
}